// Round 6
// baseline (651.686 us; speedup 1.0000x reference)
//
#include <hip/hip_runtime.h>
#include <hip/hip_bf16.h>
#include <math.h>

using bf16 = __hip_bfloat16;

typedef short s16x8 __attribute__((ext_vector_type(8)));
typedef short s16x4 __attribute__((ext_vector_type(4)));
typedef float f32x4 __attribute__((ext_vector_type(4)));

static __device__ __forceinline__ float s2f(short s) {
    return __uint_as_float(((unsigned)(unsigned short)s) << 16);
}
static __device__ __forceinline__ short f2s(float v) {
    bf16 b = __float2bfloat16(v);
    return *reinterpret_cast<short*>(&b);
}
static __device__ __forceinline__ float b2f(bf16 v) { return __bfloat162float(v); }
static __device__ __forceinline__ bf16  f2b(float v) { return __float2bfloat16(v); }
static __device__ __forceinline__ unsigned pack2(float a, float b) {
    return (unsigned)(unsigned short)f2s(a) | ((unsigned)(unsigned short)f2s(b) << 16);
}

// 64-col bf16 LDS tile, XOR-swizzled 16B blocks
static __device__ __forceinline__ int lswz(int row, int col) {
    return row * 64 + ((((col >> 3) ^ row) & 7) << 3) + (col & 7);
}
static __device__ __forceinline__ int lbase(int row, int col) {
    return row * 64 + ((((col >> 3) ^ row) & 7) << 3);
}
static __device__ __forceinline__ s16x8 ld8(const short* p) {
    return *(const s16x8*)p;
}
static __device__ __forceinline__ f32x4 mfma16(s16x8 a, s16x8 b, f32x4 c) {
    return __builtin_amdgcn_mfma_f32_16x16x32_bf16(a, b, c, 0, 0, 0);
}

constexpr int B_   = 8;
constexpr int CIN_ = 3;
constexpr int H_   = 256;
constexpr int W_   = 256;
constexpr int ED_  = 64;
constexpr float EPS_ = 1e-5f;

// bf16 weight scratch layout (elements, inside d_out)
constexpr int WQ_OFF  = 0;       // qkv_w 192x64
constexpr int WP_OFF  = 12288;   // proj_w 64x64
constexpr int W1_OFF  = 16384;   // fc1_w 256x64
constexpr int W2_OFF  = 32768;   // fc2_w 64x256
constexpr int WTOT    = 49152;

// region class for shifted-window mask (SHIFT=4, WS=8)
static __device__ __forceinline__ int clsf(int tok, int eh, int ew) {
    int ch = eh ? (1 + ((tok >> 3) >= 4)) : 0;
    int cw = ew ? (1 + ((tok & 7) >= 4)) : 0;
    return ch * 3 + cw;
}

// ---------------------------------------------------------------------------
// Kernel 0: convert GEMM weights fp32 -> bf16 into scratch (d_out head).
// ---------------------------------------------------------------------------
__global__ __launch_bounds__(256) void k_prep(
    const float* __restrict__ qkvw, const float* __restrict__ projw,
    const float* __restrict__ fc1w, const float* __restrict__ fc2w,
    short* __restrict__ wb)
{
    int e = (blockIdx.x * 256 + threadIdx.x) * 8;
    const float* src;
    if (e < WP_OFF)       src = qkvw + e;
    else if (e < W1_OFF)  src = projw + (e - WP_OFF);
    else if (e < W2_OFF)  src = fc1w + (e - W1_OFF);
    else                  src = fc2w + (e - W2_OFF);
    float4 v0 = *(const float4*)src;
    float4 v1 = *(const float4*)(src + 4);
    s16x8 o = { f2s(v0.x), f2s(v0.y), f2s(v0.z), f2s(v0.w),
                f2s(v1.x), f2s(v1.y), f2s(v1.z), f2s(v1.w) };
    *(s16x8*)&wb[e] = o;
}

// ---------------------------------------------------------------------------
// Kernel 1: conv embed 3x3, CIN=3 -> ED=64, NCHW f32 in -> NHWC bf16 out.
// ---------------------------------------------------------------------------
__global__ __launch_bounds__(256) void k_conv_embed(
    const float* __restrict__ x, const float* __restrict__ we,
    const float* __restrict__ be, bf16* __restrict__ xe)
{
    const int t    = threadIdx.x;
    const int wv   = t >> 6;
    const int lane = t & 63;
    const int hb   = blockIdx.x;          // b*256 + h
    const int h    = hb & 255;
    const int b    = hb >> 8;
    const int col  = wv * 64 + lane;

    const float* xb = x + (size_t)b * (CIN_ * H_ * W_);

    float xr[27];
#pragma unroll
    for (int ci = 0; ci < 3; ++ci)
#pragma unroll
        for (int kh = 0; kh < 3; ++kh) {
            int hy = h + kh - 1;
#pragma unroll
            for (int kw = 0; kw < 3; ++kw) {
                int wx = col + kw - 1;
                bool ok = ((unsigned)hy < 256u) & ((unsigned)wx < 256u);
                xr[ci * 9 + kh * 3 + kw] = ok ? xb[ci * 65536 + hy * 256 + wx] : 0.f;
            }
        }

    unsigned pk[32];
#pragma unroll 4
    for (int op = 0; op < 32; ++op) {
        float a0 = be[2 * op];
        float a1 = be[2 * op + 1];
        const float* w0 = we + (2 * op) * 27;
#pragma unroll
        for (int k = 0; k < 27; ++k) {
            a0 += xr[k] * w0[k];
            a1 += xr[k] * w0[27 + k];
        }
        pk[op] = pack2(a0, a1);
    }

    size_t pixel = (size_t)hb * 256 + col;
    uint4* dst = (uint4*)((short*)xe + pixel * 64);
#pragma unroll
    for (int i = 0; i < 8; ++i) dst[i] = *(uint4*)&pk[i * 4];
}

// ---------------------------------------------------------------------------
// Kernel 2: shifted-window attention, MFMA. One block (256 thr) per window.
// wave = head. Weights direct-from-global (bf16). Swapped QK^T (S^T = K Q^T)
// -> softmax 2-shuffle reduce, P kept in registers, PV A-frags via shuffles.
// LDS 32 KB, 3 barriers.
// ---------------------------------------------------------------------------
__global__ __launch_bounds__(256, 3) void k_attn(
    const bf16* __restrict__ xe, const short* __restrict__ wq,
    const float* __restrict__ qkv_b, const short* __restrict__ wp,
    const float* __restrict__ proj_b, const float* __restrict__ n1_g,
    const float* __restrict__ n1_b, bf16* __restrict__ x_out)
{
    __shared__ short s_x[64 * 64];     // Xn (post-LN); later O
    __shared__ short s_q[64 * 64];     // Q (scaled)
    __shared__ short s_k[64 * 64];     // K
    __shared__ short s_vt[64 * 64];    // V^T [d][tok]

    const int t    = threadIdx.x;
    const int w    = t >> 6;
    const int lane = t & 63;
    const int lr   = lane & 15;
    const int lhi  = lane >> 4;

    const int bi  = blockIdx.x;
    const int b   = bi >> 10;
    const int wh  = (bi >> 5) & 31;
    const int wwi = bi & 31;
    const int eh  = (wh == 31), ew = (wwi == 31);

    const bf16* xeb = xe + (size_t)b * (H_ * W_ * ED_);
    const f32x4 cz = { 0.f, 0.f, 0.f, 0.f };

    // ---- stage 1: token load (rolled) + LN -> s_x ----
    {
        int n = t >> 2, q = t & 3;
        int hp = (wh * 8 + (n >> 3) + 4) & 255;
        int wp_ = (wwi * 8 + (n & 7) + 4) & 255;
        const short* src = (const short*)xeb + (hp * 256 + wp_) * 64 + q * 16;
        s16x8 u0 = *(const s16x8*)src;
        s16x8 u1 = *(const s16x8*)(src + 8);
        float v[16];
        float s = 0.f, sq = 0.f;
#pragma unroll
        for (int j = 0; j < 8; ++j) { v[j] = s2f(u0[j]); v[8 + j] = s2f(u1[j]); }
#pragma unroll
        for (int j = 0; j < 16; ++j) { s += v[j]; sq += v[j] * v[j]; }
        s  += __shfl_xor(s, 1);  s  += __shfl_xor(s, 2);
        sq += __shfl_xor(sq, 1); sq += __shfl_xor(sq, 2);
        float m = s * (1.f / 64.f);
        float rstd = rsqrtf(sq * (1.f / 64.f) - m * m + EPS_);
        s16x8 w0, w1;
#pragma unroll
        for (int j = 0; j < 8; ++j) {
            w0[j] = f2s((v[j] - m) * rstd * n1_g[q * 16 + j] + n1_b[q * 16 + j]);
            w1[j] = f2s((v[8 + j] - m) * rstd * n1_g[q * 16 + 8 + j] + n1_b[q * 16 + 8 + j]);
        }
        *(s16x8*)&s_x[lbase(n, q * 16)]     = w0;
        *(s16x8*)&s_x[lbase(n, q * 16 + 8)] = w1;
    }
    __syncthreads();

    // ---- stage 2: QKV GEMMs (B-fragments direct from global bf16) ----
    {
        int arow = w * 16 + lr;
        s16x8 a0 = ld8(&s_x[lbase(arow, lhi * 8)]);
        s16x8 a1 = ld8(&s_x[lbase(arow, 32 + lhi * 8)]);
#pragma unroll
        for (int nt = 0; nt < 8; ++nt) {        // Q: nt 0..3, K: nt 4..7
            int brow = nt * 16 + lr;
            s16x8 b0 = *(const s16x8*)&wq[brow * 64 + lhi * 8];
            s16x8 b1 = *(const s16x8*)&wq[brow * 64 + 32 + lhi * 8];
            f32x4 c = mfma16(a1, b1, mfma16(a0, b0, cz));
            float bias = qkv_b[brow];
#pragma unroll
            for (int r = 0; r < 4; ++r) {
                int tok = w * 16 + lhi * 4 + r;
                float val = c[r] + bias;
                if (nt < 4) { val *= 0.25f; s_q[lswz(tok, nt * 16 + lr)] = f2s(val); }
                else        {               s_k[lswz(tok, (nt - 4) * 16 + lr)] = f2s(val); }
            }
        }
        // V^T
        s16x8 av0 = *(const s16x8*)&wq[(128 + w * 16 + lr) * 64 + lhi * 8];
        s16x8 av1 = *(const s16x8*)&wq[(128 + w * 16 + lr) * 64 + 32 + lhi * 8];
#pragma unroll
        for (int nt = 0; nt < 4; ++nt) {
            s16x8 b0 = ld8(&s_x[lbase(nt * 16 + lr, lhi * 8)]);
            s16x8 b1 = ld8(&s_x[lbase(nt * 16 + lr, 32 + lhi * 8)]);
            f32x4 c = mfma16(av1, b1, mfma16(av0, b0, cz));
#pragma unroll
            for (int r = 0; r < 4; ++r) {
                int d = w * 16 + lhi * 4 + r;
                s_vt[lswz(d, nt * 16 + lr)] = f2s(c[r] + qkv_b[128 + d]);
            }
        }
    }
    __syncthreads();

    // ---- stage 3: S^T = K Q^T per head + softmax -> packed P in registers ----
    // D[row=kt=mt*16+lhi*4+r][col=q=nt*16+lr]
    const int h = w;
    uint2 pk[4][4];                     // [q-block][kt-block], 4 bf16 (r0..r3)
    {
        const s16x8 z8 = { 0, 0, 0, 0, 0, 0, 0, 0 };
        s16x8 kb[4];
#pragma unroll
        for (int mt = 0; mt < 4; ++mt)
            kb[mt] = (lhi >= 2) ? z8
                   : ld8(&s_k[lbase(mt * 16 + lr, h * 16 + (lhi & 1) * 8)]);
#pragma unroll
        for (int nt = 0; nt < 4; ++nt) {
            s16x8 qb = ld8(&s_q[lbase(nt * 16 + lr, h * 16 + (lhi & 1) * 8)]);
            f32x4 S[4];
#pragma unroll
            for (int mt = 0; mt < 4; ++mt)
                S[mt] = mfma16(kb[mt], qb, cz);

            if (eh | ew) {
                int qc = clsf(nt * 16 + lr, eh, ew);
#pragma unroll
                for (int mt = 0; mt < 4; ++mt)
#pragma unroll
                    for (int r = 0; r < 4; ++r) {
                        int kc = clsf(mt * 16 + lhi * 4 + r, eh, ew);
                        S[mt][r] += (kc != qc) ? -100.f : 0.f;
                    }
            }
            float mx = -1e30f;
#pragma unroll
            for (int mt = 0; mt < 4; ++mt)
#pragma unroll
                for (int r = 0; r < 4; ++r) mx = fmaxf(mx, S[mt][r]);
            mx = fmaxf(mx, __shfl_xor(mx, 16));
            mx = fmaxf(mx, __shfl_xor(mx, 32));
            float ev[4][4];
            float sm = 0.f;
#pragma unroll
            for (int mt = 0; mt < 4; ++mt)
#pragma unroll
                for (int r = 0; r < 4; ++r) {
                    ev[mt][r] = __expf(S[mt][r] - mx);
                    sm += ev[mt][r];
                }
            sm += __shfl_xor(sm, 16);
            sm += __shfl_xor(sm, 32);
            float inv = 1.f / sm;
#pragma unroll
            for (int mt = 0; mt < 4; ++mt) {
                pk[nt][mt].x = pack2(ev[mt][0] * inv, ev[mt][1] * inv);
                pk[nt][mt].y = pack2(ev[mt][2] * inv, ev[mt][3] * inv);
            }
        }
    }

    // ---- stage 4: O = P V ; P A-fragments built by intra-wave shuffles ----
    {
        f32x4 O[4] = { cz, cz, cz, cz };
        const int  srcl  = lr + 32 * (lane & 16 ? 1 : 0) ; // lr + 32*(lhi&1)
        const int  srcl2 = lr + 32 * (lhi & 1);
        (void)srcl;
        const bool selhi = (lhi >= 2);
#pragma unroll
        for (int ks = 0; ks < 2; ++ks) {
            s16x8 bv = ld8(&s_vt[lbase(h * 16 + lr, ks * 32 + lhi * 8)]);
#pragma unroll
            for (int mo = 0; mo < 4; ++mo) {
                unsigned lAx = (unsigned)__shfl((int)pk[mo][ks * 2 + 0].x, srcl2);
                unsigned lAy = (unsigned)__shfl((int)pk[mo][ks * 2 + 0].y, srcl2);
                unsigned lBx = (unsigned)__shfl((int)pk[mo][ks * 2 + 1].x, srcl2);
                unsigned lBy = (unsigned)__shfl((int)pk[mo][ks * 2 + 1].y, srcl2);
                unsigned hAx = (unsigned)__shfl((int)pk[mo][ks * 2 + 0].x, srcl2 + 16);
                unsigned hAy = (unsigned)__shfl((int)pk[mo][ks * 2 + 0].y, srcl2 + 16);
                unsigned hBx = (unsigned)__shfl((int)pk[mo][ks * 2 + 1].x, srcl2 + 16);
                unsigned hBy = (unsigned)__shfl((int)pk[mo][ks * 2 + 1].y, srcl2 + 16);
                uint4 pa;
                pa.x = selhi ? lBx : lAx;
                pa.y = selhi ? lBy : lAy;
                pa.z = selhi ? hBx : hAx;
                pa.w = selhi ? hBy : hAy;
                O[mo] = mfma16(*(s16x8*)&pa, bv, O[mo]);
            }
        }
        // store O -> s_x overlay (Xn dead since stage-2 barrier)
#pragma unroll
        for (int mo = 0; mo < 4; ++mo)
#pragma unroll
            for (int r = 0; r < 4; ++r)
                s_x[lswz(mo * 16 + lhi * 4 + r, h * 16 + lr)] = f2s(O[mo][r]);
    }
    __syncthreads();

    // ---- stage 5: proj + residual + store (window-reverse + roll fused) ----
    {
        int arow = w * 16 + lr;
        s16x8 a0 = ld8(&s_x[lbase(arow, lhi * 8)]);
        s16x8 a1 = ld8(&s_x[lbase(arow, 32 + lhi * 8)]);
        size_t rowbase[4];
#pragma unroll
        for (int r = 0; r < 4; ++r) {
            int tok = w * 16 + lhi * 4 + r;
            int hp = (wh * 8 + (tok >> 3) + 4) & 255;
            int wpx = (wwi * 8 + (tok & 7) + 4) & 255;
            rowbase[r] = (size_t)(hp * 256 + wpx) * 64;
        }
        const size_t bbase = (size_t)b * (H_ * W_ * ED_);
#pragma unroll
        for (int nt = 0; nt < 4; ++nt) {
            s16x8 b0 = *(const s16x8*)&wp[(nt * 16 + lr) * 64 + lhi * 8];
            s16x8 b1 = *(const s16x8*)&wp[(nt * 16 + lr) * 64 + 32 + lhi * 8];
            f32x4 c = mfma16(a1, b1, mfma16(a0, b0, cz));
            float bias = proj_b[nt * 16 + lr];
#pragma unroll
            for (int r = 0; r < 4; ++r) {
                size_t gi = rowbase[r] + nt * 16 + lr;
                float val = c[r] + bias + b2f(xeb[gi]);
                x_out[bbase + gi] = f2b(val);
            }
        }
    }
}

// ---------------------------------------------------------------------------
// Kernel 3: LN2 + fc1 + GELU + fc2 + residual. 128 tokens/block, 8 waves.
// Weights direct-from-global bf16; s_x/s_h wave-private stripes -> 0 barriers.
// ---------------------------------------------------------------------------
__global__ __launch_bounds__(512, 8) void k_mlp(
    const bf16* __restrict__ xo, const short* __restrict__ w1,
    const float* __restrict__ fc1_b, const short* __restrict__ w2,
    const float* __restrict__ fc2_b, const float* __restrict__ n2_g,
    const float* __restrict__ n2_b, bf16* __restrict__ xf)
{
    __shared__ short s_x[128 * 64];    // normalized tokens (wave-private rows)
    __shared__ short s_h[128 * 64];    // hidden chunk (wave-private rows)

    const int t    = threadIdx.x;
    const int w    = t >> 6;
    const int lane = t & 63;
    const int lr   = lane & 15;
    const int lhi  = lane >> 4;
    const size_t tok0 = (size_t)blockIdx.x * 128;
    const short* xos = (const short*)xo;

    // LN: 4 threads per token; thread t handles row t>>2 (wave-private)
    {
        int n = t >> 2, q = t & 3;
        const short* src = xos + (tok0 + n) * 64 + q * 16;
        s16x8 u0 = *(const s16x8*)src;
        s16x8 u1 = *(const s16x8*)(src + 8);
        float v[16];
        float s = 0.f, sq = 0.f;
#pragma unroll
        for (int j = 0; j < 8; ++j) { v[j] = s2f(u0[j]); v[8 + j] = s2f(u1[j]); }
#pragma unroll
        for (int j = 0; j < 16; ++j) { s += v[j]; sq += v[j] * v[j]; }
        s  += __shfl_xor(s, 1);  s  += __shfl_xor(s, 2);
        sq += __shfl_xor(sq, 1); sq += __shfl_xor(sq, 2);
        float m = s * (1.f / 64.f);
        float rstd = rsqrtf(sq * (1.f / 64.f) - m * m + EPS_);
        s16x8 w0, w1_;
#pragma unroll
        for (int j = 0; j < 8; ++j) {
            w0[j]  = f2s((v[j] - m) * rstd * n2_g[q * 16 + j] + n2_b[q * 16 + j]);
            w1_[j] = f2s((v[8 + j] - m) * rstd * n2_g[q * 16 + 8 + j] + n2_b[q * 16 + 8 + j]);
        }
        *(s16x8*)&s_x[lbase(n, q * 16)]     = w0;
        *(s16x8*)&s_x[lbase(n, q * 16 + 8)] = w1_;
    }

    const f32x4 cz = { 0.f, 0.f, 0.f, 0.f };
    f32x4 acc[4] = { cz, cz, cz, cz };
    const int arow = w * 16 + lr;

    s16x8 a0 = ld8(&s_x[lbase(arow, lhi * 8)]);
    s16x8 a1 = ld8(&s_x[lbase(arow, 32 + lhi * 8)]);

    for (int k = 0; k < 4; ++k) {
        // fc1 chunk + GELU -> s_h (own 16-row stripe)
#pragma unroll
        for (int nt = 0; nt < 4; ++nt) {
            const short* bp = &w1[(k * 64 + nt * 16 + lr) * 64 + lhi * 8];
            s16x8 b0 = *(const s16x8*)bp;
            s16x8 b1 = *(const s16x8*)(bp + 32);
            f32x4 c = mfma16(a1, b1, mfma16(a0, b0, cz));
            float bias = fc1_b[k * 64 + nt * 16 + lr];
#pragma unroll
            for (int r = 0; r < 4; ++r) {
                float hv = c[r] + bias;
                hv = 0.5f * hv * (1.f + erff(hv * 0.70710678118f));
                s_h[lswz(w * 16 + lhi * 4 + r, nt * 16 + lr)] = f2s(hv);
            }
        }
        // fc2 partial (reads own stripe; same-wave DS order)
        s16x8 h0 = ld8(&s_h[lbase(arow, lhi * 8)]);
        s16x8 h1 = ld8(&s_h[lbase(arow, 32 + lhi * 8)]);
#pragma unroll
        for (int nt = 0; nt < 4; ++nt) {
            const short* bp2 = &w2[(nt * 16 + lr) * 256 + k * 64 + lhi * 8];
            s16x8 b0 = *(const s16x8*)bp2;
            s16x8 b1 = *(const s16x8*)(bp2 + 32);
            acc[nt] = mfma16(h1, b1, mfma16(h0, b0, acc[nt]));
        }
    }

    // epilogue: bias + residual + store
#pragma unroll
    for (int nt = 0; nt < 4; ++nt) {
        float bias = fc2_b[nt * 16 + lr];
#pragma unroll
        for (int r = 0; r < 4; ++r) {
            int tok = w * 16 + lhi * 4 + r;
            size_t gi = (tok0 + tok) * 64 + nt * 16 + lr;
            float v = acc[nt][r] + bias + s2f(xos[gi]);
            ((short*)xf)[gi] = f2s(v);
        }
    }
}

// ---------------------------------------------------------------------------
// Kernel 4: conv up 3x3, ED=64 -> CIN=3, MFMA GEMM (M=pixels, N=3 pad 16,
// K=9 taps x 64 ci). Block = 64-pixel row segment, 4 waves x 16 pixels.
// ---------------------------------------------------------------------------
__global__ __launch_bounds__(256) void k_conv_up(
    const float* __restrict__ x, const bf16* __restrict__ xf,
    const float* __restrict__ wu, const float* __restrict__ bu,
    float* __restrict__ out)
{
    __shared__ short s_t[198 * 64];    // xf tile [kh*66 + wx_local][ci], swizzled
    __shared__ short s_bf[1152 * 8];   // B-fragments [(tap*2+half)*64 + lane][8]
    __shared__ float s_wu[1728];       // wu fp32 staging

    const int t    = threadIdx.x;
    const int pix0 = blockIdx.x * 64;
    const int b    = pix0 >> 16;
    const int h    = (pix0 >> 8) & 255;
    const int w0   = pix0 & 255;

    const short* xfs = (const short*)xf;

    for (int e = t; e < 1584; e += 256) {
        int rc = e >> 3, j8 = e & 7;
        int hy_l = (unsigned)rc / 66u;
        int wx_l = rc - hy_l * 66;
        int hy = h + hy_l - 1;
        int wx = w0 + wx_l - 1;
        s16x8 v = { 0, 0, 0, 0, 0, 0, 0, 0 };
        if (((unsigned)hy < 256u) & ((unsigned)wx < 256u))
            v = *(const s16x8*)&xfs[((size_t)((b * 256 + hy) * 256 + wx)) * 64 + j8 * 8];
        *(s16x8*)&s_t[lbase(rc, j8 * 8)] = v;
    }
    for (int e = t; e < 1728; e += 256) s_wu[e] = wu[e];
    __syncthreads();

    for (int fid = t; fid < 1152; fid += 256) {
        int tap  = fid >> 7;
        int half = (fid >> 6) & 1;
        int ln   = fid & 63;
        int co   = ln & 15;
        s16x8 v = { 0, 0, 0, 0, 0, 0, 0, 0 };
        if (co < 3) {
            int ci0 = half * 32 + (ln >> 4) * 8;
#pragma unroll
            for (int j = 0; j < 8; ++j)
                v[j] = f2s(s_wu[(co * 64 + ci0 + j) * 9 + tap]);
        }
        *(s16x8*)&s_bf[fid * 8] = v;
    }
    __syncthreads();

    const int wv   = t >> 6;
    const int lane = t & 63;
    const int lr   = lane & 15;
    const int lhi  = lane >> 4;

    f32x4 acc = { 0.f, 0.f, 0.f, 0.f };
#pragma unroll
    for (int kh = 0; kh < 3; ++kh)
#pragma unroll
        for (int kw = 0; kw < 3; ++kw) {
            const int tap = kh * 3 + kw;
            const int R   = kh * 66 + wv * 16 + lr + kw;
#pragma unroll
            for (int half = 0; half < 2; ++half) {
                s16x8 a   = ld8(&s_t[lbase(R, half * 32 + lhi * 8)]);
                s16x8 bfr = ld8(&s_bf[((tap * 2 + half) * 64 + lane) * 8]);
                acc = mfma16(a, bfr, acc);
            }
        }

    if (lr < 3) {
        const int co = lr;
        const int wp = wv * 16 + lhi * 4;
        size_t o0 = (size_t)b * 3 * 65536 + (size_t)co * 65536 + (size_t)h * 256 + w0 + wp;
        float4 xv = *(const float4*)&x[o0];
        float bias = bu[co];
        float4 ov;
        ov.x = acc[0] + bias + xv.x;
        ov.y = acc[1] + bias + xv.y;
        ov.z = acc[2] + bias + xv.z;
        ov.w = acc[3] + bias + xv.w;
        *(float4*)&out[o0] = ov;
    }
}

// ---------------------------------------------------------------------------
extern "C" void kernel_launch(void* const* d_in, const int* in_sizes, int n_in,
                              void* d_out, int out_size, void* d_ws, size_t ws_size,
                              hipStream_t stream)
{
    const float* x     = (const float*)d_in[0];
    const float* cew   = (const float*)d_in[1];
    const float* ceb   = (const float*)d_in[2];
    const float* n1g   = (const float*)d_in[3];
    const float* n1b   = (const float*)d_in[4];
    const float* qkvw  = (const float*)d_in[5];
    const float* qkvb  = (const float*)d_in[6];
    const float* projw = (const float*)d_in[7];
    const float* projb = (const float*)d_in[8];
    const float* n2g   = (const float*)d_in[9];
    const float* n2b   = (const float*)d_in[10];
    const float* fc1w  = (const float*)d_in[11];
    const float* fc1b  = (const float*)d_in[12];
    const float* fc2w  = (const float*)d_in[13];
    const float* fc2b  = (const float*)d_in[14];
    const float* cuw   = (const float*)d_in[15];
    const float* cub   = (const float*)d_in[16];
    float* out = (float*)d_out;

    const size_t planeElems = (size_t)B_ * H_ * W_ * ED_;   // 33.5M
    bf16* xe = (bf16*)d_ws;                                  // also x_final later
    bf16* xo = (bf16*)((char*)d_ws + planeElems * sizeof(bf16));

    // bf16 weight scratch lives in the head of d_out; conv_up fully
    // overwrites d_out at the end of the launch.
    short* wb = (short*)d_out;

    hipLaunchKernelGGL(k_prep, dim3(WTOT / 2048), dim3(256), 0, stream,
                       qkvw, projw, fc1w, fc2w, wb);
    hipLaunchKernelGGL(k_conv_embed, dim3(2048), dim3(256), 0, stream, x, cew, ceb, xe);
    hipLaunchKernelGGL(k_attn,       dim3(8192), dim3(256), 0, stream,
                       xe, wb + WQ_OFF, qkvb, wb + WP_OFF, projb, n1g, n1b, xo);
    hipLaunchKernelGGL(k_mlp,        dim3(4096), dim3(512), 0, stream,
                       xo, wb + W1_OFF, fc1b, wb + W2_OFF, fc2b, n2g, n2b, xe);
    hipLaunchKernelGGL(k_conv_up,    dim3(8192), dim3(256), 0, stream, x, xe, cuw, cub, out);
}

// Round 8
// 613.036 us; speedup vs baseline: 1.0630x; 1.0630x over previous
//
#include <hip/hip_runtime.h>
#include <hip/hip_bf16.h>
#include <math.h>

using bf16 = __hip_bfloat16;

typedef short s16x8 __attribute__((ext_vector_type(8)));
typedef short s16x4 __attribute__((ext_vector_type(4)));
typedef float f32x4 __attribute__((ext_vector_type(4)));

static __device__ __forceinline__ float s2f(short s) {
    return __uint_as_float(((unsigned)(unsigned short)s) << 16);
}
static __device__ __forceinline__ short f2s(float v) {
    bf16 b = __float2bfloat16(v);
    return *reinterpret_cast<short*>(&b);
}
static __device__ __forceinline__ float b2f(bf16 v) { return __bfloat162float(v); }
static __device__ __forceinline__ bf16  f2b(float v) { return __float2bfloat16(v); }
static __device__ __forceinline__ unsigned pack2(float a, float b) {
    return (unsigned)(unsigned short)f2s(a) | ((unsigned)(unsigned short)f2s(b) << 16);
}

// 64-col bf16 LDS tile, XOR-swizzled 16B blocks
static __device__ __forceinline__ int lswz(int row, int col) {
    return row * 64 + ((((col >> 3) ^ row) & 7) << 3) + (col & 7);
}
static __device__ __forceinline__ int lbase(int row, int col) {
    return row * 64 + ((((col >> 3) ^ row) & 7) << 3);
}
static __device__ __forceinline__ s16x8 ld8(const short* p) {
    return *(const s16x8*)p;
}
static __device__ __forceinline__ f32x4 mfma16(s16x8 a, s16x8 b, f32x4 c) {
    return __builtin_amdgcn_mfma_f32_16x16x32_bf16(a, b, c, 0, 0, 0);
}

constexpr int B_   = 8;
constexpr int CIN_ = 3;
constexpr int H_   = 256;
constexpr int W_   = 256;
constexpr int ED_  = 64;
constexpr float EPS_ = 1e-5f;

// bf16 weight scratch layout (elements, inside d_out)
constexpr int WQ_OFF  = 0;       // qkv_w 192x64
constexpr int WP_OFF  = 12288;   // proj_w 64x64
constexpr int W1_OFF  = 16384;   // fc1_w 256x64
constexpr int W2_OFF  = 32768;   // fc2_w 64x256
constexpr int WTOT    = 49152;

// region class for shifted-window mask (SHIFT=4, WS=8)
static __device__ __forceinline__ int clsf(int tok, int eh, int ew) {
    int ch = eh ? (1 + ((tok >> 3) >= 4)) : 0;
    int cw = ew ? (1 + ((tok & 7) >= 4)) : 0;
    return ch * 3 + cw;
}

// ---------------------------------------------------------------------------
// Kernel 0: convert GEMM weights fp32 -> bf16 into scratch (d_out head).
// ---------------------------------------------------------------------------
__global__ __launch_bounds__(256) void k_prep(
    const float* __restrict__ qkvw, const float* __restrict__ projw,
    const float* __restrict__ fc1w, const float* __restrict__ fc2w,
    short* __restrict__ wb)
{
    int e = (blockIdx.x * 256 + threadIdx.x) * 8;
    const float* src;
    if (e < WP_OFF)       src = qkvw + e;
    else if (e < W1_OFF)  src = projw + (e - WP_OFF);
    else if (e < W2_OFF)  src = fc1w + (e - W1_OFF);
    else                  src = fc2w + (e - W2_OFF);
    float4 v0 = *(const float4*)src;
    float4 v1 = *(const float4*)(src + 4);
    s16x8 o = { f2s(v0.x), f2s(v0.y), f2s(v0.z), f2s(v0.w),
                f2s(v1.x), f2s(v1.y), f2s(v1.z), f2s(v1.w) };
    *(s16x8*)&wb[e] = o;
}

// ---------------------------------------------------------------------------
// Kernel 1: conv embed 3x3, CIN=3 -> ED=64, NCHW f32 in -> NHWC bf16 out.
// ---------------------------------------------------------------------------
__global__ __launch_bounds__(256) void k_conv_embed(
    const float* __restrict__ x, const float* __restrict__ we,
    const float* __restrict__ be, bf16* __restrict__ xe)
{
    const int t    = threadIdx.x;
    const int wv   = t >> 6;
    const int lane = t & 63;
    const int hb   = blockIdx.x;          // b*256 + h
    const int h    = hb & 255;
    const int b    = hb >> 8;
    const int col  = wv * 64 + lane;

    const float* xb = x + (size_t)b * (CIN_ * H_ * W_);

    float xr[27];
#pragma unroll
    for (int ci = 0; ci < 3; ++ci)
#pragma unroll
        for (int kh = 0; kh < 3; ++kh) {
            int hy = h + kh - 1;
#pragma unroll
            for (int kw = 0; kw < 3; ++kw) {
                int wx = col + kw - 1;
                bool ok = ((unsigned)hy < 256u) & ((unsigned)wx < 256u);
                xr[ci * 9 + kh * 3 + kw] = ok ? xb[ci * 65536 + hy * 256 + wx] : 0.f;
            }
        }

    unsigned pk[32];
#pragma unroll 4
    for (int op = 0; op < 32; ++op) {
        float a0 = be[2 * op];
        float a1 = be[2 * op + 1];
        const float* w0 = we + (2 * op) * 27;
#pragma unroll
        for (int k = 0; k < 27; ++k) {
            a0 += xr[k] * w0[k];
            a1 += xr[k] * w0[27 + k];
        }
        pk[op] = pack2(a0, a1);
    }

    size_t pixel = (size_t)hb * 256 + col;
    uint4* dst = (uint4*)((short*)xe + pixel * 64);
#pragma unroll
    for (int i = 0; i < 8; ++i) dst[i] = *(uint4*)&pk[i * 4];
}

// ---------------------------------------------------------------------------
// Kernel 2: shifted-window attention, MFMA. One block (256 thr) per window.
// wave = head. Weights direct-from-global (bf16). Swapped QK^T (S^T = K Q^T)
// -> softmax 2-shuffle reduce, P kept in registers, PV A-frags via shuffles.
// LDS 32 KB, 3 barriers.
// ---------------------------------------------------------------------------
__global__ __launch_bounds__(256, 3) void k_attn(
    const bf16* __restrict__ xe, const short* __restrict__ wq,
    const float* __restrict__ qkv_b, const short* __restrict__ wp,
    const float* __restrict__ proj_b, const float* __restrict__ n1_g,
    const float* __restrict__ n1_b, bf16* __restrict__ x_out)
{
    __shared__ short s_x[64 * 64];     // Xn (post-LN); later O
    __shared__ short s_q[64 * 64];     // Q (scaled)
    __shared__ short s_k[64 * 64];     // K
    __shared__ short s_vt[64 * 64];    // V^T [d][tok]

    const int t    = threadIdx.x;
    const int w    = t >> 6;
    const int lane = t & 63;
    const int lr   = lane & 15;
    const int lhi  = lane >> 4;

    const int bi  = blockIdx.x;
    const int b   = bi >> 10;
    const int wh  = (bi >> 5) & 31;
    const int wwi = bi & 31;
    const int eh  = (wh == 31), ew = (wwi == 31);

    const bf16* xeb = xe + (size_t)b * (H_ * W_ * ED_);
    const f32x4 cz = { 0.f, 0.f, 0.f, 0.f };

    // ---- stage 1: token load (rolled) + LN -> s_x ----
    {
        int n = t >> 2, q = t & 3;
        int hp = (wh * 8 + (n >> 3) + 4) & 255;
        int wp_ = (wwi * 8 + (n & 7) + 4) & 255;
        const short* src = (const short*)xeb + (hp * 256 + wp_) * 64 + q * 16;
        s16x8 u0 = *(const s16x8*)src;
        s16x8 u1 = *(const s16x8*)(src + 8);
        float v[16];
        float s = 0.f, sq = 0.f;
#pragma unroll
        for (int j = 0; j < 8; ++j) { v[j] = s2f(u0[j]); v[8 + j] = s2f(u1[j]); }
#pragma unroll
        for (int j = 0; j < 16; ++j) { s += v[j]; sq += v[j] * v[j]; }
        s  += __shfl_xor(s, 1);  s  += __shfl_xor(s, 2);
        sq += __shfl_xor(sq, 1); sq += __shfl_xor(sq, 2);
        float m = s * (1.f / 64.f);
        float rstd = rsqrtf(sq * (1.f / 64.f) - m * m + EPS_);
        s16x8 w0, w1;
#pragma unroll
        for (int j = 0; j < 8; ++j) {
            w0[j] = f2s((v[j] - m) * rstd * n1_g[q * 16 + j] + n1_b[q * 16 + j]);
            w1[j] = f2s((v[8 + j] - m) * rstd * n1_g[q * 16 + 8 + j] + n1_b[q * 16 + 8 + j]);
        }
        *(s16x8*)&s_x[lbase(n, q * 16)]     = w0;
        *(s16x8*)&s_x[lbase(n, q * 16 + 8)] = w1;
    }
    __syncthreads();

    // ---- stage 2: QKV GEMMs (B-fragments direct from global bf16) ----
    {
        int arow = w * 16 + lr;
        s16x8 a0 = ld8(&s_x[lbase(arow, lhi * 8)]);
        s16x8 a1 = ld8(&s_x[lbase(arow, 32 + lhi * 8)]);
#pragma unroll
        for (int nt = 0; nt < 8; ++nt) {        // Q: nt 0..3, K: nt 4..7
            int brow = nt * 16 + lr;
            s16x8 b0 = *(const s16x8*)&wq[brow * 64 + lhi * 8];
            s16x8 b1 = *(const s16x8*)&wq[brow * 64 + 32 + lhi * 8];
            f32x4 c = mfma16(a1, b1, mfma16(a0, b0, cz));
            float bias = qkv_b[brow];
#pragma unroll
            for (int r = 0; r < 4; ++r) {
                int tok = w * 16 + lhi * 4 + r;
                float val = c[r] + bias;
                if (nt < 4) { val *= 0.25f; s_q[lswz(tok, nt * 16 + lr)] = f2s(val); }
                else        {               s_k[lswz(tok, (nt - 4) * 16 + lr)] = f2s(val); }
            }
        }
        // V^T
        s16x8 av0 = *(const s16x8*)&wq[(128 + w * 16 + lr) * 64 + lhi * 8];
        s16x8 av1 = *(const s16x8*)&wq[(128 + w * 16 + lr) * 64 + 32 + lhi * 8];
#pragma unroll
        for (int nt = 0; nt < 4; ++nt) {
            s16x8 b0 = ld8(&s_x[lbase(nt * 16 + lr, lhi * 8)]);
            s16x8 b1 = ld8(&s_x[lbase(nt * 16 + lr, 32 + lhi * 8)]);
            f32x4 c = mfma16(av1, b1, mfma16(av0, b0, cz));
#pragma unroll
            for (int r = 0; r < 4; ++r) {
                int d = w * 16 + lhi * 4 + r;
                s_vt[lswz(d, nt * 16 + lr)] = f2s(c[r] + qkv_b[128 + d]);
            }
        }
    }
    __syncthreads();

    // ---- stage 3: S^T = K Q^T per head + softmax -> packed P in registers ----
    // D[row=kt=mt*16+lhi*4+r][col=q=nt*16+lr]
    const int h = w;
    uint2 pk[4][4];                     // [q-block][kt-block], 4 bf16 (r0..r3)
    {
        const s16x8 z8 = { 0, 0, 0, 0, 0, 0, 0, 0 };
        s16x8 kb[4];
#pragma unroll
        for (int mt = 0; mt < 4; ++mt)
            kb[mt] = (lhi >= 2) ? z8
                   : ld8(&s_k[lbase(mt * 16 + lr, h * 16 + (lhi & 1) * 8)]);
#pragma unroll
        for (int nt = 0; nt < 4; ++nt) {
            s16x8 qb = ld8(&s_q[lbase(nt * 16 + lr, h * 16 + (lhi & 1) * 8)]);
            f32x4 S[4];
#pragma unroll
            for (int mt = 0; mt < 4; ++mt)
                S[mt] = mfma16(kb[mt], qb, cz);

            if (eh | ew) {
                int qc = clsf(nt * 16 + lr, eh, ew);
#pragma unroll
                for (int mt = 0; mt < 4; ++mt)
#pragma unroll
                    for (int r = 0; r < 4; ++r) {
                        int kc = clsf(mt * 16 + lhi * 4 + r, eh, ew);
                        S[mt][r] += (kc != qc) ? -100.f : 0.f;
                    }
            }
            float mx = -1e30f;
#pragma unroll
            for (int mt = 0; mt < 4; ++mt)
#pragma unroll
                for (int r = 0; r < 4; ++r) mx = fmaxf(mx, S[mt][r]);
            mx = fmaxf(mx, __shfl_xor(mx, 16));
            mx = fmaxf(mx, __shfl_xor(mx, 32));
            float ev[4][4];
            float sm = 0.f;
#pragma unroll
            for (int mt = 0; mt < 4; ++mt)
#pragma unroll
                for (int r = 0; r < 4; ++r) {
                    ev[mt][r] = __expf(S[mt][r] - mx);
                    sm += ev[mt][r];
                }
            sm += __shfl_xor(sm, 16);
            sm += __shfl_xor(sm, 32);
            float inv = 1.f / sm;
#pragma unroll
            for (int mt = 0; mt < 4; ++mt) {
                pk[nt][mt].x = pack2(ev[mt][0] * inv, ev[mt][1] * inv);
                pk[nt][mt].y = pack2(ev[mt][2] * inv, ev[mt][3] * inv);
            }
        }
    }

    // ---- stage 4: O = P V ; P A-fragments built by intra-wave shuffles ----
    {
        f32x4 O[4] = { cz, cz, cz, cz };
        const int  srcl2 = lr + 32 * (lhi & 1);
        const bool selhi = (lhi >= 2);
#pragma unroll
        for (int ks = 0; ks < 2; ++ks) {
            s16x8 bv = ld8(&s_vt[lbase(h * 16 + lr, ks * 32 + lhi * 8)]);
#pragma unroll
            for (int mo = 0; mo < 4; ++mo) {
                unsigned lAx = (unsigned)__shfl((int)pk[mo][ks * 2 + 0].x, srcl2);
                unsigned lAy = (unsigned)__shfl((int)pk[mo][ks * 2 + 0].y, srcl2);
                unsigned lBx = (unsigned)__shfl((int)pk[mo][ks * 2 + 1].x, srcl2);
                unsigned lBy = (unsigned)__shfl((int)pk[mo][ks * 2 + 1].y, srcl2);
                unsigned hAx = (unsigned)__shfl((int)pk[mo][ks * 2 + 0].x, srcl2 + 16);
                unsigned hAy = (unsigned)__shfl((int)pk[mo][ks * 2 + 0].y, srcl2 + 16);
                unsigned hBx = (unsigned)__shfl((int)pk[mo][ks * 2 + 1].x, srcl2 + 16);
                unsigned hBy = (unsigned)__shfl((int)pk[mo][ks * 2 + 1].y, srcl2 + 16);
                uint4 pa;
                pa.x = selhi ? lBx : lAx;
                pa.y = selhi ? lBy : lAy;
                pa.z = selhi ? hBx : hAx;
                pa.w = selhi ? hBy : hAy;
                O[mo] = mfma16(*(s16x8*)&pa, bv, O[mo]);
            }
        }
        // store O -> s_x overlay (Xn dead since stage-2 barrier)
#pragma unroll
        for (int mo = 0; mo < 4; ++mo)
#pragma unroll
            for (int r = 0; r < 4; ++r)
                s_x[lswz(mo * 16 + lhi * 4 + r, h * 16 + lr)] = f2s(O[mo][r]);
    }
    __syncthreads();

    // ---- stage 5: proj + residual + store (window-reverse + roll fused) ----
    {
        int arow = w * 16 + lr;
        s16x8 a0 = ld8(&s_x[lbase(arow, lhi * 8)]);
        s16x8 a1 = ld8(&s_x[lbase(arow, 32 + lhi * 8)]);
        size_t rowbase[4];
#pragma unroll
        for (int r = 0; r < 4; ++r) {
            int tok = w * 16 + lhi * 4 + r;
            int hp = (wh * 8 + (tok >> 3) + 4) & 255;
            int wpx = (wwi * 8 + (tok & 7) + 4) & 255;
            rowbase[r] = (size_t)(hp * 256 + wpx) * 64;
        }
        const size_t bbase = (size_t)b * (H_ * W_ * ED_);
#pragma unroll
        for (int nt = 0; nt < 4; ++nt) {
            s16x8 b0 = *(const s16x8*)&wp[(nt * 16 + lr) * 64 + lhi * 8];
            s16x8 b1 = *(const s16x8*)&wp[(nt * 16 + lr) * 64 + 32 + lhi * 8];
            f32x4 c = mfma16(a1, b1, mfma16(a0, b0, cz));
            float bias = proj_b[nt * 16 + lr];
#pragma unroll
            for (int r = 0; r < 4; ++r) {
                size_t gi = rowbase[r] + nt * 16 + lr;
                float val = c[r] + bias + b2f(xeb[gi]);
                x_out[bbase + gi] = f2b(val);
            }
        }
    }
}

// ---------------------------------------------------------------------------
// Kernel 3: LN2 + fc1 + GELU + fc2 + residual. 128 tokens/block, 8 waves.
// Weights direct-from-global bf16; s_x/s_h wave-private stripes -> 0 barriers.
// launch_bounds (512,4): VGPR cap 128 — (512,8) caused scratch spill (R6).
// ---------------------------------------------------------------------------
__global__ __launch_bounds__(512, 4) void k_mlp(
    const bf16* __restrict__ xo, const short* __restrict__ w1,
    const float* __restrict__ fc1_b, const short* __restrict__ w2,
    const float* __restrict__ fc2_b, const float* __restrict__ n2_g,
    const float* __restrict__ n2_b, bf16* __restrict__ xf)
{
    __shared__ short s_x[128 * 64];    // normalized tokens (wave-private rows)
    __shared__ short s_h[128 * 64];    // hidden chunk (wave-private rows)

    const int t    = threadIdx.x;
    const int w    = t >> 6;
    const int lane = t & 63;
    const int lr   = lane & 15;
    const int lhi  = lane >> 4;
    const size_t tok0 = (size_t)blockIdx.x * 128;
    const short* xos = (const short*)xo;

    // LN: 4 threads per token; thread t handles row t>>2 (wave-private)
    {
        int n = t >> 2, q = t & 3;
        const short* src = xos + (tok0 + n) * 64 + q * 16;
        s16x8 u0 = *(const s16x8*)src;
        s16x8 u1 = *(const s16x8*)(src + 8);
        float v[16];
        float s = 0.f, sq = 0.f;
#pragma unroll
        for (int j = 0; j < 8; ++j) { v[j] = s2f(u0[j]); v[8 + j] = s2f(u1[j]); }
#pragma unroll
        for (int j = 0; j < 16; ++j) { s += v[j]; sq += v[j] * v[j]; }
        s  += __shfl_xor(s, 1);  s  += __shfl_xor(s, 2);
        sq += __shfl_xor(sq, 1); sq += __shfl_xor(sq, 2);
        float m = s * (1.f / 64.f);
        float rstd = rsqrtf(sq * (1.f / 64.f) - m * m + EPS_);
        s16x8 w0, w1_;
#pragma unroll
        for (int j = 0; j < 8; ++j) {
            w0[j]  = f2s((v[j] - m) * rstd * n2_g[q * 16 + j] + n2_b[q * 16 + j]);
            w1_[j] = f2s((v[8 + j] - m) * rstd * n2_g[q * 16 + 8 + j] + n2_b[q * 16 + 8 + j]);
        }
        *(s16x8*)&s_x[lbase(n, q * 16)]     = w0;
        *(s16x8*)&s_x[lbase(n, q * 16 + 8)] = w1_;
    }

    const f32x4 cz = { 0.f, 0.f, 0.f, 0.f };
    f32x4 acc[4] = { cz, cz, cz, cz };
    const int arow = w * 16 + lr;

    s16x8 a0 = ld8(&s_x[lbase(arow, lhi * 8)]);
    s16x8 a1 = ld8(&s_x[lbase(arow, 32 + lhi * 8)]);

    for (int k = 0; k < 4; ++k) {
        // fc1 chunk + GELU -> s_h (own 16-row stripe)
#pragma unroll
        for (int nt = 0; nt < 4; ++nt) {
            const short* bp = &w1[(k * 64 + nt * 16 + lr) * 64 + lhi * 8];
            s16x8 b0 = *(const s16x8*)bp;
            s16x8 b1 = *(const s16x8*)(bp + 32);
            f32x4 c = mfma16(a1, b1, mfma16(a0, b0, cz));
            float bias = fc1_b[k * 64 + nt * 16 + lr];
#pragma unroll
            for (int r = 0; r < 4; ++r) {
                float hv = c[r] + bias;
                hv = 0.5f * hv * (1.f + erff(hv * 0.70710678118f));
                s_h[lswz(w * 16 + lhi * 4 + r, nt * 16 + lr)] = f2s(hv);
            }
        }
        // fc2 partial (reads own stripe; same-wave DS order)
        s16x8 h0 = ld8(&s_h[lbase(arow, lhi * 8)]);
        s16x8 h1 = ld8(&s_h[lbase(arow, 32 + lhi * 8)]);
#pragma unroll
        for (int nt = 0; nt < 4; ++nt) {
            const short* bp2 = &w2[(nt * 16 + lr) * 256 + k * 64 + lhi * 8];
            s16x8 b0 = *(const s16x8*)bp2;
            s16x8 b1 = *(const s16x8*)(bp2 + 32);
            acc[nt] = mfma16(h1, b1, mfma16(h0, b0, acc[nt]));
        }
    }

    // epilogue: bias + residual + store
#pragma unroll
    for (int nt = 0; nt < 4; ++nt) {
        float bias = fc2_b[nt * 16 + lr];
#pragma unroll
        for (int r = 0; r < 4; ++r) {
            int tok = w * 16 + lhi * 4 + r;
            size_t gi = (tok0 + tok) * 64 + nt * 16 + lr;
            float v = acc[nt][r] + bias + s2f(xos[gi]);
            ((short*)xf)[gi] = f2s(v);
        }
    }
}

// ---------------------------------------------------------------------------
// Kernel 4: conv up 3x3, ED=64 -> CIN=3, MFMA GEMM (M=pixels, N=3 pad 16,
// K=9 taps x 64 ci). Block = 64-pixel row segment, 4 waves x 16 pixels.
// ---------------------------------------------------------------------------
__global__ __launch_bounds__(256) void k_conv_up(
    const float* __restrict__ x, const bf16* __restrict__ xf,
    const float* __restrict__ wu, const float* __restrict__ bu,
    float* __restrict__ out)
{
    __shared__ short s_t[198 * 64];    // xf tile [kh*66 + wx_local][ci], swizzled
    __shared__ short s_bf[1152 * 8];   // B-fragments [(tap*2+half)*64 + lane][8]
    __shared__ float s_wu[1728];       // wu fp32 staging

    const int t    = threadIdx.x;
    const int pix0 = blockIdx.x * 64;
    const int b    = pix0 >> 16;
    const int h    = (pix0 >> 8) & 255;
    const int w0   = pix0 & 255;

    const short* xfs = (const short*)xf;

    for (int e = t; e < 1584; e += 256) {
        int rc = e >> 3, j8 = e & 7;
        int hy_l = (unsigned)rc / 66u;
        int wx_l = rc - hy_l * 66;
        int hy = h + hy_l - 1;
        int wx = w0 + wx_l - 1;
        s16x8 v = { 0, 0, 0, 0, 0, 0, 0, 0 };
        if (((unsigned)hy < 256u) & ((unsigned)wx < 256u))
            v = *(const s16x8*)&xfs[((size_t)((b * 256 + hy) * 256 + wx)) * 64 + j8 * 8];
        *(s16x8*)&s_t[lbase(rc, j8 * 8)] = v;
    }
    for (int e = t; e < 1728; e += 256) s_wu[e] = wu[e];
    __syncthreads();

    for (int fid = t; fid < 1152; fid += 256) {
        int tap  = fid >> 7;
        int half = (fid >> 6) & 1;
        int ln   = fid & 63;
        int co   = ln & 15;
        s16x8 v = { 0, 0, 0, 0, 0, 0, 0, 0 };
        if (co < 3) {
            int ci0 = half * 32 + (ln >> 4) * 8;
#pragma unroll
            for (int j = 0; j < 8; ++j)
                v[j] = f2s(s_wu[(co * 64 + ci0 + j) * 9 + tap]);
        }
        *(s16x8*)&s_bf[fid * 8] = v;
    }
    __syncthreads();

    const int wv   = t >> 6;
    const int lane = t & 63;
    const int lr   = lane & 15;
    const int lhi  = lane >> 4;

    f32x4 acc = { 0.f, 0.f, 0.f, 0.f };
#pragma unroll
    for (int kh = 0; kh < 3; ++kh)
#pragma unroll
        for (int kw = 0; kw < 3; ++kw) {
            const int tap = kh * 3 + kw;
            const int R   = kh * 66 + wv * 16 + lr + kw;
#pragma unroll
            for (int half = 0; half < 2; ++half) {
                s16x8 a   = ld8(&s_t[lbase(R, half * 32 + lhi * 8)]);
                s16x8 bfr = ld8(&s_bf[((tap * 2 + half) * 64 + lane) * 8]);
                acc = mfma16(a, bfr, acc);
            }
        }

    if (lr < 3) {
        const int co = lr;
        const int wp = wv * 16 + lhi * 4;
        size_t o0 = (size_t)b * 3 * 65536 + (size_t)co * 65536 + (size_t)h * 256 + w0 + wp;
        float4 xv = *(const float4*)&x[o0];
        float bias = bu[co];
        float4 ov;
        ov.x = acc[0] + bias + xv.x;
        ov.y = acc[1] + bias + xv.y;
        ov.z = acc[2] + bias + xv.z;
        ov.w = acc[3] + bias + xv.w;
        *(float4*)&out[o0] = ov;
    }
}

// ---------------------------------------------------------------------------
extern "C" void kernel_launch(void* const* d_in, const int* in_sizes, int n_in,
                              void* d_out, int out_size, void* d_ws, size_t ws_size,
                              hipStream_t stream)
{
    const float* x     = (const float*)d_in[0];
    const float* cew   = (const float*)d_in[1];
    const float* ceb   = (const float*)d_in[2];
    const float* n1g   = (const float*)d_in[3];
    const float* n1b   = (const float*)d_in[4];
    const float* qkvw  = (const float*)d_in[5];
    const float* qkvb  = (const float*)d_in[6];
    const float* projw = (const float*)d_in[7];
    const float* projb = (const float*)d_in[8];
    const float* n2g   = (const float*)d_in[9];
    const float* n2b   = (const float*)d_in[10];
    const float* fc1w  = (const float*)d_in[11];
    const float* fc1b  = (const float*)d_in[12];
    const float* fc2w  = (const float*)d_in[13];
    const float* fc2b  = (const float*)d_in[14];
    const float* cuw   = (const float*)d_in[15];
    const float* cub   = (const float*)d_in[16];
    float* out = (float*)d_out;

    const size_t planeElems = (size_t)B_ * H_ * W_ * ED_;   // 33.5M
    bf16* xe = (bf16*)d_ws;                                  // also x_final later
    bf16* xo = (bf16*)((char*)d_ws + planeElems * sizeof(bf16));

    // bf16 weight scratch lives in the head of d_out; conv_up fully
    // overwrites d_out at the end of the launch.
    short* wb = (short*)d_out;

    hipLaunchKernelGGL(k_prep, dim3(WTOT / 2048), dim3(256), 0, stream,
                       qkvw, projw, fc1w, fc2w, wb);
    hipLaunchKernelGGL(k_conv_embed, dim3(2048), dim3(256), 0, stream, x, cew, ceb, xe);
    hipLaunchKernelGGL(k_attn,       dim3(8192), dim3(256), 0, stream,
                       xe, wb + WQ_OFF, qkvb, wb + WP_OFF, projb, n1g, n1b, xo);
    hipLaunchKernelGGL(k_mlp,        dim3(4096), dim3(512), 0, stream,
                       xo, wb + W1_OFF, fc1b, wb + W2_OFF, fc2b, n2g, n2b, xe);
    hipLaunchKernelGGL(k_conv_up,    dim3(8192), dim3(256), 0, stream, x, xe, cuw, cub, out);
}

// Round 9
// 436.884 us; speedup vs baseline: 1.4917x; 1.4032x over previous
//
#include <hip/hip_runtime.h>
#include <hip/hip_bf16.h>
#include <math.h>

using bf16 = __hip_bfloat16;

typedef short s16x8 __attribute__((ext_vector_type(8)));
typedef short s16x4 __attribute__((ext_vector_type(4)));
typedef float f32x4 __attribute__((ext_vector_type(4)));

static __device__ __forceinline__ float s2f(short s) {
    return __uint_as_float(((unsigned)(unsigned short)s) << 16);
}
static __device__ __forceinline__ short f2s(float v) {
    bf16 b = __float2bfloat16(v);
    return *reinterpret_cast<short*>(&b);
}
static __device__ __forceinline__ float b2f(bf16 v) { return __bfloat162float(v); }
static __device__ __forceinline__ bf16  f2b(float v) { return __float2bfloat16(v); }
static __device__ __forceinline__ unsigned pack2(float a, float b) {
    return (unsigned)(unsigned short)f2s(a) | ((unsigned)(unsigned short)f2s(b) << 16);
}

// 64-col bf16 LDS tile, XOR-swizzled 16B blocks
static __device__ __forceinline__ int lswz(int row, int col) {
    return row * 64 + ((((col >> 3) ^ row) & 7) << 3) + (col & 7);
}
static __device__ __forceinline__ int lbase(int row, int col) {
    return row * 64 + ((((col >> 3) ^ row) & 7) << 3);
}
static __device__ __forceinline__ s16x8 ld8(const short* p) {
    return *(const s16x8*)p;
}
static __device__ __forceinline__ f32x4 mfma16(s16x8 a, s16x8 b, f32x4 c) {
    return __builtin_amdgcn_mfma_f32_16x16x32_bf16(a, b, c, 0, 0, 0);
}

constexpr int B_   = 8;
constexpr int CIN_ = 3;
constexpr int H_   = 256;
constexpr int W_   = 256;
constexpr int ED_  = 64;
constexpr float EPS_ = 1e-5f;

// Fragment-layout weight scratch (elements, inside d_out head).
// Each fragment = 512 bf16, element (lane l, j) at frag*512 + l*8 + j.
// Frag ids: qkv 0..23 (blk 0..11 x half), proj 24..31, fc1 32..63, fc2 64..95.
constexpr int WQ_OFF  = 0;       // qkv  frags  0..23
constexpr int WP_OFF  = 12288;   // proj frags 24..31
constexpr int W1_OFF  = 16384;   // fc1  frags 32..63
constexpr int W2_OFF  = 32768;   // fc2  frags 64..95
constexpr int NFRAG   = 96;

// region class for shifted-window mask (SHIFT=4, WS=8)
static __device__ __forceinline__ int clsf(int tok, int eh, int ew) {
    int ch = eh ? (1 + ((tok >> 3) >= 4)) : 0;
    int cw = ew ? (1 + ((tok & 7) >= 4)) : 0;
    return ch * 3 + cw;
}

// ---------------------------------------------------------------------------
// Kernel 0: weights fp32 -> bf16 MFMA-fragment layout (coalesced 16B/lane
// reads downstream). 6144 threads = 96 frags x 64 lanes.
// ---------------------------------------------------------------------------
__global__ __launch_bounds__(256) void k_prep(
    const float* __restrict__ qkvw, const float* __restrict__ projw,
    const float* __restrict__ fc1w, const float* __restrict__ fc2w,
    short* __restrict__ wb)
{
    int g    = blockIdx.x * 256 + threadIdx.x;   // 0..6143
    int l    = g & 63;
    int frag = g >> 6;                           // 0..95
    int lr   = l & 15, lhi = l >> 4;

    const float* src;
    if (frag < 24) {                 // qkv_w [192][64]
        int blk = frag >> 1, half = frag & 1;
        src = qkvw + (blk * 16 + lr) * 64 + half * 32 + lhi * 8;
    } else if (frag < 32) {          // proj_w [64][64]
        int f = frag - 24; int blk = f >> 1, half = f & 1;
        src = projw + (blk * 16 + lr) * 64 + half * 32 + lhi * 8;
    } else if (frag < 64) {          // fc1_w [256][64]
        int f = frag - 32; int blk = f >> 1, half = f & 1;
        src = fc1w + (blk * 16 + lr) * 64 + half * 32 + lhi * 8;
    } else {                         // fc2_w [64][256]
        int f = frag - 64; int pair = f >> 1, half = f & 1;
        int k = pair >> 2, nt = pair & 3;
        src = fc2w + (nt * 16 + lr) * 256 + k * 64 + half * 32 + lhi * 8;
    }
    float4 v0 = *(const float4*)src;
    float4 v1 = *(const float4*)(src + 4);
    s16x8 o = { f2s(v0.x), f2s(v0.y), f2s(v0.z), f2s(v0.w),
                f2s(v1.x), f2s(v1.y), f2s(v1.z), f2s(v1.w) };
    *(s16x8*)&wb[frag * 512 + l * 8] = o;
}

// ---------------------------------------------------------------------------
// Kernel 1: conv embed 3x3, CIN=3 -> ED=64, NCHW f32 in -> NHWC bf16 out.
// ---------------------------------------------------------------------------
__global__ __launch_bounds__(256) void k_conv_embed(
    const float* __restrict__ x, const float* __restrict__ we,
    const float* __restrict__ be, bf16* __restrict__ xe)
{
    const int t    = threadIdx.x;
    const int wv   = t >> 6;
    const int lane = t & 63;
    const int hb   = blockIdx.x;          // b*256 + h
    const int h    = hb & 255;
    const int b    = hb >> 8;
    const int col  = wv * 64 + lane;

    const float* xb = x + (size_t)b * (CIN_ * H_ * W_);

    float xr[27];
#pragma unroll
    for (int ci = 0; ci < 3; ++ci)
#pragma unroll
        for (int kh = 0; kh < 3; ++kh) {
            int hy = h + kh - 1;
#pragma unroll
            for (int kw = 0; kw < 3; ++kw) {
                int wx = col + kw - 1;
                bool ok = ((unsigned)hy < 256u) & ((unsigned)wx < 256u);
                xr[ci * 9 + kh * 3 + kw] = ok ? xb[ci * 65536 + hy * 256 + wx] : 0.f;
            }
        }

    unsigned pk[32];
#pragma unroll 4
    for (int op = 0; op < 32; ++op) {
        float a0 = be[2 * op];
        float a1 = be[2 * op + 1];
        const float* w0 = we + (2 * op) * 27;
#pragma unroll
        for (int k = 0; k < 27; ++k) {
            a0 += xr[k] * w0[k];
            a1 += xr[k] * w0[27 + k];
        }
        pk[op] = pack2(a0, a1);
    }

    size_t pixel = (size_t)hb * 256 + col;
    uint4* dst = (uint4*)((short*)xe + pixel * 64);
#pragma unroll
    for (int i = 0; i < 8; ++i) dst[i] = *(uint4*)&pk[i * 4];
}

// ---------------------------------------------------------------------------
// Kernel 2: shifted-window attention, MFMA. One block (256 thr) per window.
// wave = head. Weight fragments direct-from-global, coalesced (frag layout).
// Swapped QK^T (S^T = K Q^T), P in registers, PV A-frags via shuffles.
// ---------------------------------------------------------------------------
__global__ __launch_bounds__(256, 3) void k_attn(
    const bf16* __restrict__ xe, const short* __restrict__ wq,
    const float* __restrict__ qkv_b, const short* __restrict__ wp,
    const float* __restrict__ proj_b, const float* __restrict__ n1_g,
    const float* __restrict__ n1_b, bf16* __restrict__ x_out)
{
    __shared__ short s_x[64 * 64];     // Xn (post-LN); later O
    __shared__ short s_q[64 * 64];     // Q (scaled)
    __shared__ short s_k[64 * 64];     // K
    __shared__ short s_vt[64 * 64];    // V^T [d][tok]

    const int t    = threadIdx.x;
    const int w    = t >> 6;
    const int lane = t & 63;
    const int lr   = lane & 15;
    const int lhi  = lane >> 4;

    const int bi  = blockIdx.x;
    const int b   = bi >> 10;
    const int wh  = (bi >> 5) & 31;
    const int wwi = bi & 31;
    const int eh  = (wh == 31), ew = (wwi == 31);

    const bf16* xeb = xe + (size_t)b * (H_ * W_ * ED_);
    const f32x4 cz = { 0.f, 0.f, 0.f, 0.f };

    // ---- stage 1: token load (rolled) + LN -> s_x ----
    {
        int n = t >> 2, q = t & 3;
        int hp = (wh * 8 + (n >> 3) + 4) & 255;
        int wp_ = (wwi * 8 + (n & 7) + 4) & 255;
        const short* src = (const short*)xeb + (hp * 256 + wp_) * 64 + q * 16;
        s16x8 u0 = *(const s16x8*)src;
        s16x8 u1 = *(const s16x8*)(src + 8);
        float v[16];
        float s = 0.f, sq = 0.f;
#pragma unroll
        for (int j = 0; j < 8; ++j) { v[j] = s2f(u0[j]); v[8 + j] = s2f(u1[j]); }
#pragma unroll
        for (int j = 0; j < 16; ++j) { s += v[j]; sq += v[j] * v[j]; }
        s  += __shfl_xor(s, 1);  s  += __shfl_xor(s, 2);
        sq += __shfl_xor(sq, 1); sq += __shfl_xor(sq, 2);
        float m = s * (1.f / 64.f);
        float rstd = rsqrtf(sq * (1.f / 64.f) - m * m + EPS_);
        s16x8 w0, w1;
#pragma unroll
        for (int j = 0; j < 8; ++j) {
            w0[j] = f2s((v[j] - m) * rstd * n1_g[q * 16 + j] + n1_b[q * 16 + j]);
            w1[j] = f2s((v[8 + j] - m) * rstd * n1_g[q * 16 + 8 + j] + n1_b[q * 16 + 8 + j]);
        }
        *(s16x8*)&s_x[lbase(n, q * 16)]     = w0;
        *(s16x8*)&s_x[lbase(n, q * 16 + 8)] = w1;
    }
    __syncthreads();

    // ---- stage 2: QKV GEMMs (fragment loads fully coalesced) ----
    {
        int arow = w * 16 + lr;
        s16x8 a0 = ld8(&s_x[lbase(arow, lhi * 8)]);
        s16x8 a1 = ld8(&s_x[lbase(arow, 32 + lhi * 8)]);
#pragma unroll
        for (int nt = 0; nt < 8; ++nt) {        // Q: nt 0..3, K: nt 4..7
            s16x8 b0 = *(const s16x8*)&wq[(nt * 2 + 0) * 512 + lane * 8];
            s16x8 b1 = *(const s16x8*)&wq[(nt * 2 + 1) * 512 + lane * 8];
            f32x4 c = mfma16(a1, b1, mfma16(a0, b0, cz));
            float bias = qkv_b[nt * 16 + lr];
#pragma unroll
            for (int r = 0; r < 4; ++r) {
                int tok = w * 16 + lhi * 4 + r;
                float val = c[r] + bias;
                if (nt < 4) { val *= 0.25f; s_q[lswz(tok, nt * 16 + lr)] = f2s(val); }
                else        {               s_k[lswz(tok, (nt - 4) * 16 + lr)] = f2s(val); }
            }
        }
        // V^T: A = Wv fragment block (8 + w)
        s16x8 av0 = *(const s16x8*)&wq[((8 + w) * 2 + 0) * 512 + lane * 8];
        s16x8 av1 = *(const s16x8*)&wq[((8 + w) * 2 + 1) * 512 + lane * 8];
#pragma unroll
        for (int nt = 0; nt < 4; ++nt) {
            s16x8 b0 = ld8(&s_x[lbase(nt * 16 + lr, lhi * 8)]);
            s16x8 b1 = ld8(&s_x[lbase(nt * 16 + lr, 32 + lhi * 8)]);
            f32x4 c = mfma16(av1, b1, mfma16(av0, b0, cz));
#pragma unroll
            for (int r = 0; r < 4; ++r) {
                int d = w * 16 + lhi * 4 + r;
                s_vt[lswz(d, nt * 16 + lr)] = f2s(c[r] + qkv_b[128 + d]);
            }
        }
    }
    __syncthreads();

    // ---- stage 3: S^T = K Q^T per head + softmax -> packed P in registers ----
    const int h = w;
    uint2 pk[4][4];                     // [q-block][kt-block], 4 bf16 (r0..r3)
    {
        const s16x8 z8 = { 0, 0, 0, 0, 0, 0, 0, 0 };
        s16x8 kb[4];
#pragma unroll
        for (int mt = 0; mt < 4; ++mt)
            kb[mt] = (lhi >= 2) ? z8
                   : ld8(&s_k[lbase(mt * 16 + lr, h * 16 + (lhi & 1) * 8)]);
#pragma unroll
        for (int nt = 0; nt < 4; ++nt) {
            s16x8 qb = ld8(&s_q[lbase(nt * 16 + lr, h * 16 + (lhi & 1) * 8)]);
            f32x4 S[4];
#pragma unroll
            for (int mt = 0; mt < 4; ++mt)
                S[mt] = mfma16(kb[mt], qb, cz);

            if (eh | ew) {
                int qc = clsf(nt * 16 + lr, eh, ew);
#pragma unroll
                for (int mt = 0; mt < 4; ++mt)
#pragma unroll
                    for (int r = 0; r < 4; ++r) {
                        int kc = clsf(mt * 16 + lhi * 4 + r, eh, ew);
                        S[mt][r] += (kc != qc) ? -100.f : 0.f;
                    }
            }
            float mx = -1e30f;
#pragma unroll
            for (int mt = 0; mt < 4; ++mt)
#pragma unroll
                for (int r = 0; r < 4; ++r) mx = fmaxf(mx, S[mt][r]);
            mx = fmaxf(mx, __shfl_xor(mx, 16));
            mx = fmaxf(mx, __shfl_xor(mx, 32));
            float ev[4][4];
            float sm = 0.f;
#pragma unroll
            for (int mt = 0; mt < 4; ++mt)
#pragma unroll
                for (int r = 0; r < 4; ++r) {
                    ev[mt][r] = __expf(S[mt][r] - mx);
                    sm += ev[mt][r];
                }
            sm += __shfl_xor(sm, 16);
            sm += __shfl_xor(sm, 32);
            float inv = 1.f / sm;
#pragma unroll
            for (int mt = 0; mt < 4; ++mt) {
                pk[nt][mt].x = pack2(ev[mt][0] * inv, ev[mt][1] * inv);
                pk[nt][mt].y = pack2(ev[mt][2] * inv, ev[mt][3] * inv);
            }
        }
    }

    // ---- stage 4: O = P V ; P A-fragments built by intra-wave shuffles ----
    {
        f32x4 O[4] = { cz, cz, cz, cz };
        const int  srcl2 = lr + 32 * (lhi & 1);
        const bool selhi = (lhi >= 2);
#pragma unroll
        for (int ks = 0; ks < 2; ++ks) {
            s16x8 bv = ld8(&s_vt[lbase(h * 16 + lr, ks * 32 + lhi * 8)]);
#pragma unroll
            for (int mo = 0; mo < 4; ++mo) {
                unsigned lAx = (unsigned)__shfl((int)pk[mo][ks * 2 + 0].x, srcl2);
                unsigned lAy = (unsigned)__shfl((int)pk[mo][ks * 2 + 0].y, srcl2);
                unsigned lBx = (unsigned)__shfl((int)pk[mo][ks * 2 + 1].x, srcl2);
                unsigned lBy = (unsigned)__shfl((int)pk[mo][ks * 2 + 1].y, srcl2);
                unsigned hAx = (unsigned)__shfl((int)pk[mo][ks * 2 + 0].x, srcl2 + 16);
                unsigned hAy = (unsigned)__shfl((int)pk[mo][ks * 2 + 0].y, srcl2 + 16);
                unsigned hBx = (unsigned)__shfl((int)pk[mo][ks * 2 + 1].x, srcl2 + 16);
                unsigned hBy = (unsigned)__shfl((int)pk[mo][ks * 2 + 1].y, srcl2 + 16);
                uint4 pa;
                pa.x = selhi ? lBx : lAx;
                pa.y = selhi ? lBy : lAy;
                pa.z = selhi ? hBx : hAx;
                pa.w = selhi ? hBy : hAy;
                O[mo] = mfma16(*(s16x8*)&pa, bv, O[mo]);
            }
        }
        // store O -> s_x overlay (Xn dead since stage-2 barrier)
#pragma unroll
        for (int mo = 0; mo < 4; ++mo)
#pragma unroll
            for (int r = 0; r < 4; ++r)
                s_x[lswz(mo * 16 + lhi * 4 + r, h * 16 + lr)] = f2s(O[mo][r]);
    }
    __syncthreads();

    // ---- stage 5: proj + residual + store (window-reverse + roll fused) ----
    {
        int arow = w * 16 + lr;
        s16x8 a0 = ld8(&s_x[lbase(arow, lhi * 8)]);
        s16x8 a1 = ld8(&s_x[lbase(arow, 32 + lhi * 8)]);
        size_t rowbase[4];
#pragma unroll
        for (int r = 0; r < 4; ++r) {
            int tok = w * 16 + lhi * 4 + r;
            int hp = (wh * 8 + (tok >> 3) + 4) & 255;
            int wpx = (wwi * 8 + (tok & 7) + 4) & 255;
            rowbase[r] = (size_t)(hp * 256 + wpx) * 64;
        }
        const size_t bbase = (size_t)b * (H_ * W_ * ED_);
#pragma unroll
        for (int nt = 0; nt < 4; ++nt) {
            s16x8 b0 = *(const s16x8*)&wp[(nt * 2 + 0) * 512 + lane * 8];
            s16x8 b1 = *(const s16x8*)&wp[(nt * 2 + 1) * 512 + lane * 8];
            f32x4 c = mfma16(a1, b1, mfma16(a0, b0, cz));
            float bias = proj_b[nt * 16 + lr];
#pragma unroll
            for (int r = 0; r < 4; ++r) {
                size_t gi = rowbase[r] + nt * 16 + lr;
                float val = c[r] + bias + b2f(xeb[gi]);
                x_out[bbase + gi] = f2b(val);
            }
        }
    }
}

// ---------------------------------------------------------------------------
// Kernel 3: LN2 + fc1 + tanh-GELU + fc2 + residual. 128 tokens/block, 8 waves.
// Fragment weights direct-from-global (coalesced); wave-private LDS stripes.
// ---------------------------------------------------------------------------
__global__ __launch_bounds__(512, 4) void k_mlp(
    const bf16* __restrict__ xo, const short* __restrict__ w1,
    const float* __restrict__ fc1_b, const short* __restrict__ w2,
    const float* __restrict__ fc2_b, const float* __restrict__ n2_g,
    const float* __restrict__ n2_b, bf16* __restrict__ xf)
{
    __shared__ short s_x[128 * 64];    // normalized tokens (wave-private rows)
    __shared__ short s_h[128 * 64];    // hidden chunk (wave-private rows)

    const int t    = threadIdx.x;
    const int w    = t >> 6;
    const int lane = t & 63;
    const int lr   = lane & 15;
    const int lhi  = lane >> 4;
    const size_t tok0 = (size_t)blockIdx.x * 128;
    const short* xos = (const short*)xo;

    // LN: 4 threads per token; thread t handles row t>>2 (wave-private)
    {
        int n = t >> 2, q = t & 3;
        const short* src = xos + (tok0 + n) * 64 + q * 16;
        s16x8 u0 = *(const s16x8*)src;
        s16x8 u1 = *(const s16x8*)(src + 8);
        float v[16];
        float s = 0.f, sq = 0.f;
#pragma unroll
        for (int j = 0; j < 8; ++j) { v[j] = s2f(u0[j]); v[8 + j] = s2f(u1[j]); }
#pragma unroll
        for (int j = 0; j < 16; ++j) { s += v[j]; sq += v[j] * v[j]; }
        s  += __shfl_xor(s, 1);  s  += __shfl_xor(s, 2);
        sq += __shfl_xor(sq, 1); sq += __shfl_xor(sq, 2);
        float m = s * (1.f / 64.f);
        float rstd = rsqrtf(sq * (1.f / 64.f) - m * m + EPS_);
        s16x8 w0, w1_;
#pragma unroll
        for (int j = 0; j < 8; ++j) {
            w0[j]  = f2s((v[j] - m) * rstd * n2_g[q * 16 + j] + n2_b[q * 16 + j]);
            w1_[j] = f2s((v[8 + j] - m) * rstd * n2_g[q * 16 + 8 + j] + n2_b[q * 16 + 8 + j]);
        }
        *(s16x8*)&s_x[lbase(n, q * 16)]     = w0;
        *(s16x8*)&s_x[lbase(n, q * 16 + 8)] = w1_;
    }

    const f32x4 cz = { 0.f, 0.f, 0.f, 0.f };
    f32x4 acc[4] = { cz, cz, cz, cz };
    const int arow = w * 16 + lr;

    s16x8 a0 = ld8(&s_x[lbase(arow, lhi * 8)]);
    s16x8 a1 = ld8(&s_x[lbase(arow, 32 + lhi * 8)]);

    for (int k = 0; k < 4; ++k) {
        // fc1 chunk + GELU -> s_h (own 16-row stripe)
#pragma unroll
        for (int nt = 0; nt < 4; ++nt) {
            const short* bp = &w1[((k * 4 + nt) * 2) * 512 + lane * 8];
            s16x8 b0 = *(const s16x8*)bp;
            s16x8 b1 = *(const s16x8*)(bp + 512);
            f32x4 c = mfma16(a1, b1, mfma16(a0, b0, cz));
            float bias = fc1_b[k * 64 + nt * 16 + lr];
#pragma unroll
            for (int r = 0; r < 4; ++r) {
                float hv = c[r] + bias;
                // tanh-GELU: x * sigmoid(1.5957691*(x + 0.044715 x^3))
                float u = hv + 0.044715f * hv * hv * hv;
                hv = hv / (1.f + __expf(-1.5957691216f * u));
                s_h[lswz(w * 16 + lhi * 4 + r, nt * 16 + lr)] = f2s(hv);
            }
        }
        // fc2 partial (reads own stripe; same-wave DS order)
        s16x8 h0 = ld8(&s_h[lbase(arow, lhi * 8)]);
        s16x8 h1 = ld8(&s_h[lbase(arow, 32 + lhi * 8)]);
#pragma unroll
        for (int nt = 0; nt < 4; ++nt) {
            const short* bp2 = &w2[((k * 4 + nt) * 2) * 512 + lane * 8];
            s16x8 b0 = *(const s16x8*)bp2;
            s16x8 b1 = *(const s16x8*)(bp2 + 512);
            acc[nt] = mfma16(h1, b1, mfma16(h0, b0, acc[nt]));
        }
    }

    // epilogue: bias + residual + store
#pragma unroll
    for (int nt = 0; nt < 4; ++nt) {
        float bias = fc2_b[nt * 16 + lr];
#pragma unroll
        for (int r = 0; r < 4; ++r) {
            int tok = w * 16 + lhi * 4 + r;
            size_t gi = (tok0 + tok) * 64 + nt * 16 + lr;
            float v = acc[nt][r] + bias + s2f(xos[gi]);
            ((short*)xf)[gi] = f2s(v);
        }
    }
}

// ---------------------------------------------------------------------------
// Kernel 4: conv up 3x3, ED=64 -> CIN=3, MFMA GEMM (M=pixels, N=3 pad 16,
// K=9 taps x 64 ci). Block = 64-pixel row segment, 4 waves x 16 pixels.
// ---------------------------------------------------------------------------
__global__ __launch_bounds__(256) void k_conv_up(
    const float* __restrict__ x, const bf16* __restrict__ xf,
    const float* __restrict__ wu, const float* __restrict__ bu,
    float* __restrict__ out)
{
    __shared__ short s_t[198 * 64];    // xf tile [kh*66 + wx_local][ci], swizzled
    __shared__ short s_bf[1152 * 8];   // B-fragments [(tap*2+half)*64 + lane][8]
    __shared__ float s_wu[1728];       // wu fp32 staging

    const int t    = threadIdx.x;
    const int pix0 = blockIdx.x * 64;
    const int b    = pix0 >> 16;
    const int h    = (pix0 >> 8) & 255;
    const int w0   = pix0 & 255;

    const short* xfs = (const short*)xf;

    for (int e = t; e < 1584; e += 256) {
        int rc = e >> 3, j8 = e & 7;
        int hy_l = (unsigned)rc / 66u;
        int wx_l = rc - hy_l * 66;
        int hy = h + hy_l - 1;
        int wx = w0 + wx_l - 1;
        s16x8 v = { 0, 0, 0, 0, 0, 0, 0, 0 };
        if (((unsigned)hy < 256u) & ((unsigned)wx < 256u))
            v = *(const s16x8*)&xfs[((size_t)((b * 256 + hy) * 256 + wx)) * 64 + j8 * 8];
        *(s16x8*)&s_t[lbase(rc, j8 * 8)] = v;
    }
    for (int e = t; e < 1728; e += 256) s_wu[e] = wu[e];
    __syncthreads();

    for (int fid = t; fid < 1152; fid += 256) {
        int tap  = fid >> 7;
        int half = (fid >> 6) & 1;
        int ln   = fid & 63;
        int co   = ln & 15;
        s16x8 v = { 0, 0, 0, 0, 0, 0, 0, 0 };
        if (co < 3) {
            int ci0 = half * 32 + (ln >> 4) * 8;
#pragma unroll
            for (int j = 0; j < 8; ++j)
                v[j] = f2s(s_wu[(co * 64 + ci0 + j) * 9 + tap]);
        }
        *(s16x8*)&s_bf[fid * 8] = v;
    }
    __syncthreads();

    const int wv   = t >> 6;
    const int lane = t & 63;
    const int lr   = lane & 15;
    const int lhi  = lane >> 4;

    f32x4 acc = { 0.f, 0.f, 0.f, 0.f };
#pragma unroll
    for (int kh = 0; kh < 3; ++kh)
#pragma unroll
        for (int kw = 0; kw < 3; ++kw) {
            const int tap = kh * 3 + kw;
            const int R   = kh * 66 + wv * 16 + lr + kw;
#pragma unroll
            for (int half = 0; half < 2; ++half) {
                s16x8 a   = ld8(&s_t[lbase(R, half * 32 + lhi * 8)]);
                s16x8 bfr = ld8(&s_bf[((tap * 2 + half) * 64 + lane) * 8]);
                acc = mfma16(a, bfr, acc);
            }
        }

    if (lr < 3) {
        const int co = lr;
        const int wp = wv * 16 + lhi * 4;
        size_t o0 = (size_t)b * 3 * 65536 + (size_t)co * 65536 + (size_t)h * 256 + w0 + wp;
        float4 xv = *(const float4*)&x[o0];
        float bias = bu[co];
        float4 ov;
        ov.x = acc[0] + bias + xv.x;
        ov.y = acc[1] + bias + xv.y;
        ov.z = acc[2] + bias + xv.z;
        ov.w = acc[3] + bias + xv.w;
        *(float4*)&out[o0] = ov;
    }
}

// ---------------------------------------------------------------------------
extern "C" void kernel_launch(void* const* d_in, const int* in_sizes, int n_in,
                              void* d_out, int out_size, void* d_ws, size_t ws_size,
                              hipStream_t stream)
{
    const float* x     = (const float*)d_in[0];
    const float* cew   = (const float*)d_in[1];
    const float* ceb   = (const float*)d_in[2];
    const float* n1g   = (const float*)d_in[3];
    const float* n1b   = (const float*)d_in[4];
    const float* qkvw  = (const float*)d_in[5];
    const float* qkvb  = (const float*)d_in[6];
    const float* projw = (const float*)d_in[7];
    const float* projb = (const float*)d_in[8];
    const float* n2g   = (const float*)d_in[9];
    const float* n2b   = (const float*)d_in[10];
    const float* fc1w  = (const float*)d_in[11];
    const float* fc1b  = (const float*)d_in[12];
    const float* fc2w  = (const float*)d_in[13];
    const float* fc2b  = (const float*)d_in[14];
    const float* cuw   = (const float*)d_in[15];
    const float* cub   = (const float*)d_in[16];
    float* out = (float*)d_out;

    const size_t planeElems = (size_t)B_ * H_ * W_ * ED_;   // 33.5M
    bf16* xe = (bf16*)d_ws;                                  // also x_final later
    bf16* xo = (bf16*)((char*)d_ws + planeElems * sizeof(bf16));

    // Fragment-layout bf16 weights live in d_out head (read by attn/mlp only;
    // conv_up fully overwrites d_out at the end of the launch).
    short* wb = (short*)d_out;

    hipLaunchKernelGGL(k_prep, dim3(NFRAG * 64 / 256), dim3(256), 0, stream,
                       qkvw, projw, fc1w, fc2w, wb);
    hipLaunchKernelGGL(k_conv_embed, dim3(2048), dim3(256), 0, stream, x, cew, ceb, xe);
    hipLaunchKernelGGL(k_attn,       dim3(8192), dim3(256), 0, stream,
                       xe, wb + WQ_OFF, qkvb, wb + WP_OFF, projb, n1g, n1b, xo);
    hipLaunchKernelGGL(k_mlp,        dim3(4096), dim3(512), 0, stream,
                       xo, wb + W1_OFF, fc1b, wb + W2_OFF, fc2b, n2g, n2b, xe);
    hipLaunchKernelGGL(k_conv_up,    dim3(8192), dim3(256), 0, stream, x, xe, cuw, cub, out);
}

// Round 10
// 411.502 us; speedup vs baseline: 1.5837x; 1.0617x over previous
//
#include <hip/hip_runtime.h>
#include <hip/hip_bf16.h>
#include <math.h>

using bf16 = __hip_bfloat16;

typedef short s16x8 __attribute__((ext_vector_type(8)));
typedef short s16x4 __attribute__((ext_vector_type(4)));
typedef float f32x4 __attribute__((ext_vector_type(4)));

static __device__ __forceinline__ float s2f(short s) {
    return __uint_as_float(((unsigned)(unsigned short)s) << 16);
}
static __device__ __forceinline__ short f2s(float v) {
    bf16 b = __float2bfloat16(v);
    return *reinterpret_cast<short*>(&b);
}
static __device__ __forceinline__ float b2f(bf16 v) { return __bfloat162float(v); }
static __device__ __forceinline__ bf16  f2b(float v) { return __float2bfloat16(v); }
static __device__ __forceinline__ unsigned pack2(float a, float b) {
    return (unsigned)(unsigned short)f2s(a) | ((unsigned)(unsigned short)f2s(b) << 16);
}
static __device__ __forceinline__ float frcp(float x) {
    return __builtin_amdgcn_rcpf(x);   // ~1 ulp; outputs round to bf16 anyway
}

// 64-col bf16 LDS tile, XOR-swizzled 16B blocks
static __device__ __forceinline__ int lswz(int row, int col) {
    return row * 64 + ((((col >> 3) ^ row) & 7) << 3) + (col & 7);
}
static __device__ __forceinline__ int lbase(int row, int col) {
    return row * 64 + ((((col >> 3) ^ row) & 7) << 3);
}
static __device__ __forceinline__ s16x8 ld8(const short* p) {
    return *(const s16x8*)p;
}
static __device__ __forceinline__ f32x4 mfma16(s16x8 a, s16x8 b, f32x4 c) {
    return __builtin_amdgcn_mfma_f32_16x16x32_bf16(a, b, c, 0, 0, 0);
}

constexpr int B_   = 8;
constexpr int CIN_ = 3;
constexpr int H_   = 256;
constexpr int W_   = 256;
constexpr int ED_  = 64;
constexpr float EPS_ = 1e-5f;

// Fragment-layout weight scratch (elements, inside d_out head).
// Each fragment = 512 bf16, element (lane l, j) at frag*512 + l*8 + j.
constexpr int WQ_OFF  = 0;       // qkv  frags  0..23
constexpr int WP_OFF  = 12288;   // proj frags 24..31
constexpr int W1_OFF  = 16384;   // fc1  frags 32..63
constexpr int W2_OFF  = 32768;   // fc2  frags 64..95
constexpr int NFRAG   = 96;

// region class for shifted-window mask (SHIFT=4, WS=8)
static __device__ __forceinline__ int clsf(int tok, int eh, int ew) {
    int ch = eh ? (1 + ((tok >> 3) >= 4)) : 0;
    int cw = ew ? (1 + ((tok & 7) >= 4)) : 0;
    return ch * 3 + cw;
}

// ---------------------------------------------------------------------------
// Kernel 0: weights fp32 -> bf16 MFMA-fragment layout.
// ---------------------------------------------------------------------------
__global__ __launch_bounds__(256) void k_prep(
    const float* __restrict__ qkvw, const float* __restrict__ projw,
    const float* __restrict__ fc1w, const float* __restrict__ fc2w,
    short* __restrict__ wb)
{
    int g    = blockIdx.x * 256 + threadIdx.x;   // 0..6143
    int l    = g & 63;
    int frag = g >> 6;                           // 0..95
    int lr   = l & 15, lhi = l >> 4;

    const float* src;
    if (frag < 24) {                 // qkv_w [192][64]
        int blk = frag >> 1, half = frag & 1;
        src = qkvw + (blk * 16 + lr) * 64 + half * 32 + lhi * 8;
    } else if (frag < 32) {          // proj_w [64][64]
        int f = frag - 24; int blk = f >> 1, half = f & 1;
        src = projw + (blk * 16 + lr) * 64 + half * 32 + lhi * 8;
    } else if (frag < 64) {          // fc1_w [256][64]
        int f = frag - 32; int blk = f >> 1, half = f & 1;
        src = fc1w + (blk * 16 + lr) * 64 + half * 32 + lhi * 8;
    } else {                         // fc2_w [64][256]
        int f = frag - 64; int pair = f >> 1, half = f & 1;
        int k = pair >> 2, nt = pair & 3;
        src = fc2w + (nt * 16 + lr) * 256 + k * 64 + half * 32 + lhi * 8;
    }
    float4 v0 = *(const float4*)src;
    float4 v1 = *(const float4*)(src + 4);
    s16x8 o = { f2s(v0.x), f2s(v0.y), f2s(v0.z), f2s(v0.w),
                f2s(v1.x), f2s(v1.y), f2s(v1.z), f2s(v1.w) };
    *(s16x8*)&wb[frag * 512 + l * 8] = o;
}

// ---------------------------------------------------------------------------
// Kernel 1: conv embed 3x3, CIN=3 -> ED=64, NCHW f32 in -> NHWC bf16 out.
// ---------------------------------------------------------------------------
__global__ __launch_bounds__(256) void k_conv_embed(
    const float* __restrict__ x, const float* __restrict__ we,
    const float* __restrict__ be, bf16* __restrict__ xe)
{
    const int t    = threadIdx.x;
    const int wv   = t >> 6;
    const int lane = t & 63;
    const int hb   = blockIdx.x;          // b*256 + h
    const int h    = hb & 255;
    const int b    = hb >> 8;
    const int col  = wv * 64 + lane;

    const float* xb = x + (size_t)b * (CIN_ * H_ * W_);

    float xr[27];
#pragma unroll
    for (int ci = 0; ci < 3; ++ci)
#pragma unroll
        for (int kh = 0; kh < 3; ++kh) {
            int hy = h + kh - 1;
#pragma unroll
            for (int kw = 0; kw < 3; ++kw) {
                int wx = col + kw - 1;
                bool ok = ((unsigned)hy < 256u) & ((unsigned)wx < 256u);
                xr[ci * 9 + kh * 3 + kw] = ok ? xb[ci * 65536 + hy * 256 + wx] : 0.f;
            }
        }

    unsigned pk[32];
#pragma unroll 4
    for (int op = 0; op < 32; ++op) {
        float a0 = be[2 * op];
        float a1 = be[2 * op + 1];
        const float* w0 = we + (2 * op) * 27;
#pragma unroll
        for (int k = 0; k < 27; ++k) {
            a0 += xr[k] * w0[k];
            a1 += xr[k] * w0[27 + k];
        }
        pk[op] = pack2(a0, a1);
    }

    size_t pixel = (size_t)hb * 256 + col;
    uint4* dst = (uint4*)((short*)xe + pixel * 64);
#pragma unroll
    for (int i = 0; i < 8; ++i) dst[i] = *(uint4*)&pk[i * 4];
}

// ---------------------------------------------------------------------------
// Kernel 2: shifted-window attention, MFMA. One block (256 thr) per window.
// ---------------------------------------------------------------------------
__global__ __launch_bounds__(256, 3) void k_attn(
    const bf16* __restrict__ xe, const short* __restrict__ wq,
    const float* __restrict__ qkv_b, const short* __restrict__ wp,
    const float* __restrict__ proj_b, const float* __restrict__ n1_g,
    const float* __restrict__ n1_b, bf16* __restrict__ x_out)
{
    __shared__ short s_x[64 * 64];     // Xn (post-LN); later O
    __shared__ short s_q[64 * 64];     // Q (scaled)
    __shared__ short s_k[64 * 64];     // K
    __shared__ short s_vt[64 * 64];    // V^T [d][tok]

    const int t    = threadIdx.x;
    const int w    = t >> 6;
    const int lane = t & 63;
    const int lr   = lane & 15;
    const int lhi  = lane >> 4;

    const int bi  = blockIdx.x;
    const int b   = bi >> 10;
    const int wh  = (bi >> 5) & 31;
    const int wwi = bi & 31;
    const int eh  = (wh == 31), ew = (wwi == 31);

    const bf16* xeb = xe + (size_t)b * (H_ * W_ * ED_);
    const f32x4 cz = { 0.f, 0.f, 0.f, 0.f };

    // ---- stage 1: token load (rolled) + LN -> s_x ----
    {
        int n = t >> 2, q = t & 3;
        int hp = (wh * 8 + (n >> 3) + 4) & 255;
        int wp_ = (wwi * 8 + (n & 7) + 4) & 255;
        const short* src = (const short*)xeb + (hp * 256 + wp_) * 64 + q * 16;
        s16x8 u0 = *(const s16x8*)src;
        s16x8 u1 = *(const s16x8*)(src + 8);
        float v[16];
        float s = 0.f, sq = 0.f;
#pragma unroll
        for (int j = 0; j < 8; ++j) { v[j] = s2f(u0[j]); v[8 + j] = s2f(u1[j]); }
#pragma unroll
        for (int j = 0; j < 16; ++j) { s += v[j]; sq += v[j] * v[j]; }
        s  += __shfl_xor(s, 1);  s  += __shfl_xor(s, 2);
        sq += __shfl_xor(sq, 1); sq += __shfl_xor(sq, 2);
        float m = s * (1.f / 64.f);
        float rstd = rsqrtf(sq * (1.f / 64.f) - m * m + EPS_);
        s16x8 w0, w1;
#pragma unroll
        for (int j = 0; j < 8; ++j) {
            w0[j] = f2s((v[j] - m) * rstd * n1_g[q * 16 + j] + n1_b[q * 16 + j]);
            w1[j] = f2s((v[8 + j] - m) * rstd * n1_g[q * 16 + 8 + j] + n1_b[q * 16 + 8 + j]);
        }
        *(s16x8*)&s_x[lbase(n, q * 16)]     = w0;
        *(s16x8*)&s_x[lbase(n, q * 16 + 8)] = w1;
    }
    __syncthreads();

    // ---- stage 2: QKV GEMMs (fragment loads fully coalesced) ----
    {
        int arow = w * 16 + lr;
        s16x8 a0 = ld8(&s_x[lbase(arow, lhi * 8)]);
        s16x8 a1 = ld8(&s_x[lbase(arow, 32 + lhi * 8)]);
#pragma unroll
        for (int nt = 0; nt < 8; ++nt) {        // Q: nt 0..3, K: nt 4..7
            s16x8 b0 = *(const s16x8*)&wq[(nt * 2 + 0) * 512 + lane * 8];
            s16x8 b1 = *(const s16x8*)&wq[(nt * 2 + 1) * 512 + lane * 8];
            f32x4 c = mfma16(a1, b1, mfma16(a0, b0, cz));
            float bias = qkv_b[nt * 16 + lr];
#pragma unroll
            for (int r = 0; r < 4; ++r) {
                int tok = w * 16 + lhi * 4 + r;
                float val = c[r] + bias;
                if (nt < 4) { val *= 0.25f; s_q[lswz(tok, nt * 16 + lr)] = f2s(val); }
                else        {               s_k[lswz(tok, (nt - 4) * 16 + lr)] = f2s(val); }
            }
        }
        // V^T: A = Wv fragment block (8 + w)
        s16x8 av0 = *(const s16x8*)&wq[((8 + w) * 2 + 0) * 512 + lane * 8];
        s16x8 av1 = *(const s16x8*)&wq[((8 + w) * 2 + 1) * 512 + lane * 8];
#pragma unroll
        for (int nt = 0; nt < 4; ++nt) {
            s16x8 b0 = ld8(&s_x[lbase(nt * 16 + lr, lhi * 8)]);
            s16x8 b1 = ld8(&s_x[lbase(nt * 16 + lr, 32 + lhi * 8)]);
            f32x4 c = mfma16(av1, b1, mfma16(av0, b0, cz));
#pragma unroll
            for (int r = 0; r < 4; ++r) {
                int d = w * 16 + lhi * 4 + r;
                s_vt[lswz(d, nt * 16 + lr)] = f2s(c[r] + qkv_b[128 + d]);
            }
        }
    }
    __syncthreads();

    // ---- stage 3: S^T = K Q^T per head + softmax -> packed P in registers ----
    const int h = w;
    uint2 pk[4][4];                     // [q-block][kt-block], 4 bf16 (r0..r3)
    {
        const s16x8 z8 = { 0, 0, 0, 0, 0, 0, 0, 0 };
        s16x8 kb[4];
#pragma unroll
        for (int mt = 0; mt < 4; ++mt)
            kb[mt] = (lhi >= 2) ? z8
                   : ld8(&s_k[lbase(mt * 16 + lr, h * 16 + (lhi & 1) * 8)]);
#pragma unroll
        for (int nt = 0; nt < 4; ++nt) {
            s16x8 qb = ld8(&s_q[lbase(nt * 16 + lr, h * 16 + (lhi & 1) * 8)]);
            f32x4 S[4];
#pragma unroll
            for (int mt = 0; mt < 4; ++mt)
                S[mt] = mfma16(kb[mt], qb, cz);

            if (eh | ew) {
                int qc = clsf(nt * 16 + lr, eh, ew);
#pragma unroll
                for (int mt = 0; mt < 4; ++mt)
#pragma unroll
                    for (int r = 0; r < 4; ++r) {
                        int kc = clsf(mt * 16 + lhi * 4 + r, eh, ew);
                        S[mt][r] += (kc != qc) ? -100.f : 0.f;
                    }
            }
            float mx = -1e30f;
#pragma unroll
            for (int mt = 0; mt < 4; ++mt)
#pragma unroll
                for (int r = 0; r < 4; ++r) mx = fmaxf(mx, S[mt][r]);
            mx = fmaxf(mx, __shfl_xor(mx, 16));
            mx = fmaxf(mx, __shfl_xor(mx, 32));
            float ev[4][4];
            float sm = 0.f;
#pragma unroll
            for (int mt = 0; mt < 4; ++mt)
#pragma unroll
                for (int r = 0; r < 4; ++r) {
                    ev[mt][r] = __expf(S[mt][r] - mx);
                    sm += ev[mt][r];
                }
            sm += __shfl_xor(sm, 16);
            sm += __shfl_xor(sm, 32);
            float inv = frcp(sm);
#pragma unroll
            for (int mt = 0; mt < 4; ++mt) {
                pk[nt][mt].x = pack2(ev[mt][0] * inv, ev[mt][1] * inv);
                pk[nt][mt].y = pack2(ev[mt][2] * inv, ev[mt][3] * inv);
            }
        }
    }

    // ---- stage 4: O = P V ; P A-fragments built by intra-wave shuffles ----
    {
        f32x4 O[4] = { cz, cz, cz, cz };
        const int  srcl2 = lr + 32 * (lhi & 1);
        const bool selhi = (lhi >= 2);
#pragma unroll
        for (int ks = 0; ks < 2; ++ks) {
            s16x8 bv = ld8(&s_vt[lbase(h * 16 + lr, ks * 32 + lhi * 8)]);
#pragma unroll
            for (int mo = 0; mo < 4; ++mo) {
                unsigned lAx = (unsigned)__shfl((int)pk[mo][ks * 2 + 0].x, srcl2);
                unsigned lAy = (unsigned)__shfl((int)pk[mo][ks * 2 + 0].y, srcl2);
                unsigned lBx = (unsigned)__shfl((int)pk[mo][ks * 2 + 1].x, srcl2);
                unsigned lBy = (unsigned)__shfl((int)pk[mo][ks * 2 + 1].y, srcl2);
                unsigned hAx = (unsigned)__shfl((int)pk[mo][ks * 2 + 0].x, srcl2 + 16);
                unsigned hAy = (unsigned)__shfl((int)pk[mo][ks * 2 + 0].y, srcl2 + 16);
                unsigned hBx = (unsigned)__shfl((int)pk[mo][ks * 2 + 1].x, srcl2 + 16);
                unsigned hBy = (unsigned)__shfl((int)pk[mo][ks * 2 + 1].y, srcl2 + 16);
                uint4 pa;
                pa.x = selhi ? lBx : lAx;
                pa.y = selhi ? lBy : lAy;
                pa.z = selhi ? hBx : hAx;
                pa.w = selhi ? hBy : hAy;
                O[mo] = mfma16(*(s16x8*)&pa, bv, O[mo]);
            }
        }
        // store O -> s_x overlay (Xn dead since stage-2 barrier)
#pragma unroll
        for (int mo = 0; mo < 4; ++mo)
#pragma unroll
            for (int r = 0; r < 4; ++r)
                s_x[lswz(mo * 16 + lhi * 4 + r, h * 16 + lr)] = f2s(O[mo][r]);
    }
    __syncthreads();

    // ---- stage 5: proj + residual + store (window-reverse + roll fused) ----
    {
        int arow = w * 16 + lr;
        s16x8 a0 = ld8(&s_x[lbase(arow, lhi * 8)]);
        s16x8 a1 = ld8(&s_x[lbase(arow, 32 + lhi * 8)]);
        size_t rowbase[4];
#pragma unroll
        for (int r = 0; r < 4; ++r) {
            int tok = w * 16 + lhi * 4 + r;
            int hp = (wh * 8 + (tok >> 3) + 4) & 255;
            int wpx = (wwi * 8 + (tok & 7) + 4) & 255;
            rowbase[r] = (size_t)(hp * 256 + wpx) * 64;
        }
        const size_t bbase = (size_t)b * (H_ * W_ * ED_);
#pragma unroll
        for (int nt = 0; nt < 4; ++nt) {
            s16x8 b0 = *(const s16x8*)&wp[(nt * 2 + 0) * 512 + lane * 8];
            s16x8 b1 = *(const s16x8*)&wp[(nt * 2 + 1) * 512 + lane * 8];
            f32x4 c = mfma16(a1, b1, mfma16(a0, b0, cz));
            float bias = proj_b[nt * 16 + lr];
#pragma unroll
            for (int r = 0; r < 4; ++r) {
                size_t gi = rowbase[r] + nt * 16 + lr;
                float val = c[r] + bias + b2f(xeb[gi]);
                x_out[bbase + gi] = f2b(val);
            }
        }
    }
}

// ---------------------------------------------------------------------------
// Kernel 3: LN2 + fc1 + tanh-GELU(rcp) + fc2 + residual. 128 tok/block.
// ---------------------------------------------------------------------------
__global__ __launch_bounds__(512, 4) void k_mlp(
    const bf16* __restrict__ xo, const short* __restrict__ w1,
    const float* __restrict__ fc1_b, const short* __restrict__ w2,
    const float* __restrict__ fc2_b, const float* __restrict__ n2_g,
    const float* __restrict__ n2_b, bf16* __restrict__ xf)
{
    __shared__ short s_x[128 * 64];    // normalized tokens (wave-private rows)
    __shared__ short s_h[128 * 64];    // hidden chunk (wave-private rows)

    const int t    = threadIdx.x;
    const int w    = t >> 6;
    const int lane = t & 63;
    const int lr   = lane & 15;
    const int lhi  = lane >> 4;
    const size_t tok0 = (size_t)blockIdx.x * 128;
    const short* xos = (const short*)xo;

    // LN: 4 threads per token; thread t handles row t>>2 (wave-private)
    {
        int n = t >> 2, q = t & 3;
        const short* src = xos + (tok0 + n) * 64 + q * 16;
        s16x8 u0 = *(const s16x8*)src;
        s16x8 u1 = *(const s16x8*)(src + 8);
        float v[16];
        float s = 0.f, sq = 0.f;
#pragma unroll
        for (int j = 0; j < 8; ++j) { v[j] = s2f(u0[j]); v[8 + j] = s2f(u1[j]); }
#pragma unroll
        for (int j = 0; j < 16; ++j) { s += v[j]; sq += v[j] * v[j]; }
        s  += __shfl_xor(s, 1);  s  += __shfl_xor(s, 2);
        sq += __shfl_xor(sq, 1); sq += __shfl_xor(sq, 2);
        float m = s * (1.f / 64.f);
        float rstd = rsqrtf(sq * (1.f / 64.f) - m * m + EPS_);
        s16x8 w0, w1_;
#pragma unroll
        for (int j = 0; j < 8; ++j) {
            w0[j]  = f2s((v[j] - m) * rstd * n2_g[q * 16 + j] + n2_b[q * 16 + j]);
            w1_[j] = f2s((v[8 + j] - m) * rstd * n2_g[q * 16 + 8 + j] + n2_b[q * 16 + 8 + j]);
        }
        *(s16x8*)&s_x[lbase(n, q * 16)]     = w0;
        *(s16x8*)&s_x[lbase(n, q * 16 + 8)] = w1_;
    }

    const f32x4 cz = { 0.f, 0.f, 0.f, 0.f };
    f32x4 acc[4] = { cz, cz, cz, cz };
    const int arow = w * 16 + lr;

    s16x8 a0 = ld8(&s_x[lbase(arow, lhi * 8)]);
    s16x8 a1 = ld8(&s_x[lbase(arow, 32 + lhi * 8)]);

    for (int k = 0; k < 4; ++k) {
        // fc1 chunk + GELU -> s_h (own 16-row stripe)
#pragma unroll
        for (int nt = 0; nt < 4; ++nt) {
            const short* bp = &w1[((k * 4 + nt) * 2) * 512 + lane * 8];
            s16x8 b0 = *(const s16x8*)bp;
            s16x8 b1 = *(const s16x8*)(bp + 512);
            f32x4 c = mfma16(a1, b1, mfma16(a0, b0, cz));
            float bias = fc1_b[k * 64 + nt * 16 + lr];
#pragma unroll
            for (int r = 0; r < 4; ++r) {
                float hv = c[r] + bias;
                // tanh-GELU: x * sigmoid(1.5957691*(x + 0.044715 x^3)), rcp not div
                float u = hv + 0.044715f * hv * hv * hv;
                hv = hv * frcp(1.f + __expf(-1.5957691216f * u));
                s_h[lswz(w * 16 + lhi * 4 + r, nt * 16 + lr)] = f2s(hv);
            }
        }
        // fc2 partial (reads own stripe; same-wave DS order)
        s16x8 h0 = ld8(&s_h[lbase(arow, lhi * 8)]);
        s16x8 h1 = ld8(&s_h[lbase(arow, 32 + lhi * 8)]);
#pragma unroll
        for (int nt = 0; nt < 4; ++nt) {
            const short* bp2 = &w2[((k * 4 + nt) * 2) * 512 + lane * 8];
            s16x8 b0 = *(const s16x8*)bp2;
            s16x8 b1 = *(const s16x8*)(bp2 + 512);
            acc[nt] = mfma16(h1, b1, mfma16(h0, b0, acc[nt]));
        }
    }

    // epilogue: bias + residual + store
#pragma unroll
    for (int nt = 0; nt < 4; ++nt) {
        float bias = fc2_b[nt * 16 + lr];
#pragma unroll
        for (int r = 0; r < 4; ++r) {
            int tok = w * 16 + lhi * 4 + r;
            size_t gi = (tok0 + tok) * 64 + nt * 16 + lr;
            float v = acc[nt][r] + bias + s2f(xos[gi]);
            ((short*)xf)[gi] = f2s(v);
        }
    }
}

// ---------------------------------------------------------------------------
// Kernel 4: conv up 3x3, ED=64 -> CIN=3, MFMA GEMM.
// ---------------------------------------------------------------------------
__global__ __launch_bounds__(256) void k_conv_up(
    const float* __restrict__ x, const bf16* __restrict__ xf,
    const float* __restrict__ wu, const float* __restrict__ bu,
    float* __restrict__ out)
{
    __shared__ short s_t[198 * 64];    // xf tile [kh*66 + wx_local][ci], swizzled
    __shared__ short s_bf[1152 * 8];   // B-fragments [(tap*2+half)*64 + lane][8]
    __shared__ float s_wu[1728];       // wu fp32 staging

    const int t    = threadIdx.x;
    const int pix0 = blockIdx.x * 64;
    const int b    = pix0 >> 16;
    const int h    = (pix0 >> 8) & 255;
    const int w0   = pix0 & 255;

    const short* xfs = (const short*)xf;

    for (int e = t; e < 1584; e += 256) {
        int rc = e >> 3, j8 = e & 7;
        int hy_l = (unsigned)rc / 66u;
        int wx_l = rc - hy_l * 66;
        int hy = h + hy_l - 1;
        int wx = w0 + wx_l - 1;
        s16x8 v = { 0, 0, 0, 0, 0, 0, 0, 0 };
        if (((unsigned)hy < 256u) & ((unsigned)wx < 256u))
            v = *(const s16x8*)&xfs[((size_t)((b * 256 + hy) * 256 + wx)) * 64 + j8 * 8];
        *(s16x8*)&s_t[lbase(rc, j8 * 8)] = v;
    }
    for (int e = t; e < 1728; e += 256) s_wu[e] = wu[e];
    __syncthreads();

    for (int fid = t; fid < 1152; fid += 256) {
        int tap  = fid >> 7;
        int half = (fid >> 6) & 1;
        int ln   = fid & 63;
        int co   = ln & 15;
        s16x8 v = { 0, 0, 0, 0, 0, 0, 0, 0 };
        if (co < 3) {
            int ci0 = half * 32 + (ln >> 4) * 8;
#pragma unroll
            for (int j = 0; j < 8; ++j)
                v[j] = f2s(s_wu[(co * 64 + ci0 + j) * 9 + tap]);
        }
        *(s16x8*)&s_bf[fid * 8] = v;
    }
    __syncthreads();

    const int wv   = t >> 6;
    const int lane = t & 63;
    const int lr   = lane & 15;
    const int lhi  = lane >> 4;

    f32x4 acc = { 0.f, 0.f, 0.f, 0.f };
#pragma unroll
    for (int kh = 0; kh < 3; ++kh)
#pragma unroll
        for (int kw = 0; kw < 3; ++kw) {
            const int tap = kh * 3 + kw;
            const int R   = kh * 66 + wv * 16 + lr + kw;
#pragma unroll
            for (int half = 0; half < 2; ++half) {
                s16x8 a   = ld8(&s_t[lbase(R, half * 32 + lhi * 8)]);
                s16x8 bfr = ld8(&s_bf[((tap * 2 + half) * 64 + lane) * 8]);
                acc = mfma16(a, bfr, acc);
            }
        }

    if (lr < 3) {
        const int co = lr;
        const int wp = wv * 16 + lhi * 4;
        size_t o0 = (size_t)b * 3 * 65536 + (size_t)co * 65536 + (size_t)h * 256 + w0 + wp;
        float4 xv = *(const float4*)&x[o0];
        float bias = bu[co];
        float4 ov;
        ov.x = acc[0] + bias + xv.x;
        ov.y = acc[1] + bias + xv.y;
        ov.z = acc[2] + bias + xv.z;
        ov.w = acc[3] + bias + xv.w;
        *(float4*)&out[o0] = ov;
    }
}

// ---------------------------------------------------------------------------
extern "C" void kernel_launch(void* const* d_in, const int* in_sizes, int n_in,
                              void* d_out, int out_size, void* d_ws, size_t ws_size,
                              hipStream_t stream)
{
    const float* x     = (const float*)d_in[0];
    const float* cew   = (const float*)d_in[1];
    const float* ceb   = (const float*)d_in[2];
    const float* n1g   = (const float*)d_in[3];
    const float* n1b   = (const float*)d_in[4];
    const float* qkvw  = (const float*)d_in[5];
    const float* qkvb  = (const float*)d_in[6];
    const float* projw = (const float*)d_in[7];
    const float* projb = (const float*)d_in[8];
    const float* n2g   = (const float*)d_in[9];
    const float* n2b   = (const float*)d_in[10];
    const float* fc1w  = (const float*)d_in[11];
    const float* fc1b  = (const float*)d_in[12];
    const float* fc2w  = (const float*)d_in[13];
    const float* fc2b  = (const float*)d_in[14];
    const float* cuw   = (const float*)d_in[15];
    const float* cub   = (const float*)d_in[16];
    float* out = (float*)d_out;

    const size_t planeElems = (size_t)B_ * H_ * W_ * ED_;   // 33.5M
    bf16* xe = (bf16*)d_ws;                                  // also x_final later
    bf16* xo = (bf16*)((char*)d_ws + planeElems * sizeof(bf16));

    // Fragment-layout bf16 weights live in d_out head (read by attn/mlp only;
    // conv_up fully overwrites d_out at the end of the launch).
    short* wb = (short*)d_out;

    hipLaunchKernelGGL(k_prep, dim3(NFRAG * 64 / 256), dim3(256), 0, stream,
                       qkvw, projw, fc1w, fc2w, wb);
    hipLaunchKernelGGL(k_conv_embed, dim3(2048), dim3(256), 0, stream, x, cew, ceb, xe);
    hipLaunchKernelGGL(k_attn,       dim3(8192), dim3(256), 0, stream,
                       xe, wb + WQ_OFF, qkvb, wb + WP_OFF, projb, n1g, n1b, xo);
    hipLaunchKernelGGL(k_mlp,        dim3(4096), dim3(512), 0, stream,
                       xo, wb + W1_OFF, fc1b, wb + W2_OFF, fc2b, n2g, n2b, xe);
    hipLaunchKernelGGL(k_conv_up,    dim3(8192), dim3(256), 0, stream, x, xe, cuw, cub, out);
}

// Round 11
// 405.695 us; speedup vs baseline: 1.6063x; 1.0143x over previous
//
#include <hip/hip_runtime.h>
#include <hip/hip_bf16.h>
#include <math.h>

using bf16 = __hip_bfloat16;

typedef short s16x8 __attribute__((ext_vector_type(8)));
typedef short s16x4 __attribute__((ext_vector_type(4)));
typedef float f32x4 __attribute__((ext_vector_type(4)));

static __device__ __forceinline__ float s2f(short s) {
    return __uint_as_float(((unsigned)(unsigned short)s) << 16);
}
static __device__ __forceinline__ short f2s(float v) {
    bf16 b = __float2bfloat16(v);
    return *reinterpret_cast<short*>(&b);
}
static __device__ __forceinline__ float b2f(bf16 v) { return __bfloat162float(v); }
static __device__ __forceinline__ bf16  f2b(float v) { return __float2bfloat16(v); }
static __device__ __forceinline__ unsigned pack2(float a, float b) {
    return (unsigned)(unsigned short)f2s(a) | ((unsigned)(unsigned short)f2s(b) << 16);
}
static __device__ __forceinline__ float frcp(float x) {
    return __builtin_amdgcn_rcpf(x);
}

// 64-col bf16 LDS tile, XOR-swizzled 16B blocks
static __device__ __forceinline__ int lswz(int row, int col) {
    return row * 64 + ((((col >> 3) ^ row) & 7) << 3) + (col & 7);
}
static __device__ __forceinline__ int lbase(int row, int col) {
    return row * 64 + ((((col >> 3) ^ row) & 7) << 3);
}
static __device__ __forceinline__ s16x8 ld8(const short* p) {
    return *(const s16x8*)p;
}
static __device__ __forceinline__ f32x4 mfma16(s16x8 a, s16x8 b, f32x4 c) {
    return __builtin_amdgcn_mfma_f32_16x16x32_bf16(a, b, c, 0, 0, 0);
}

constexpr int B_   = 8;
constexpr int CIN_ = 3;
constexpr int H_   = 256;
constexpr int W_   = 256;
constexpr int ED_  = 64;
constexpr float EPS_ = 1e-5f;

// Fragment-layout weight scratch (elements, inside d_out head).
constexpr int WQ_OFF  = 0;       // qkv  frags  0..23
constexpr int WP_OFF  = 12288;   // proj frags 24..31
constexpr int W1_OFF  = 16384;   // fc1  frags 32..63
constexpr int W2_OFF  = 32768;   // fc2  frags 64..95
constexpr int NFRAG   = 96;

// region class for shifted-window mask (SHIFT=4, WS=8)
static __device__ __forceinline__ int clsf(int tok, int eh, int ew) {
    int ch = eh ? (1 + ((tok >> 3) >= 4)) : 0;
    int cw = ew ? (1 + ((tok & 7) >= 4)) : 0;
    return ch * 3 + cw;
}

// ---------------------------------------------------------------------------
// Kernel 0: weights fp32 -> bf16 MFMA-fragment layout.
// ---------------------------------------------------------------------------
__global__ __launch_bounds__(256) void k_prep(
    const float* __restrict__ qkvw, const float* __restrict__ projw,
    const float* __restrict__ fc1w, const float* __restrict__ fc2w,
    short* __restrict__ wb)
{
    int g    = blockIdx.x * 256 + threadIdx.x;   // 0..6143
    int l    = g & 63;
    int frag = g >> 6;                           // 0..95
    int lr   = l & 15, lhi = l >> 4;

    const float* src;
    if (frag < 24) {                 // qkv_w [192][64]
        int blk = frag >> 1, half = frag & 1;
        src = qkvw + (blk * 16 + lr) * 64 + half * 32 + lhi * 8;
    } else if (frag < 32) {          // proj_w [64][64]
        int f = frag - 24; int blk = f >> 1, half = f & 1;
        src = projw + (blk * 16 + lr) * 64 + half * 32 + lhi * 8;
    } else if (frag < 64) {          // fc1_w [256][64]
        int f = frag - 32; int blk = f >> 1, half = f & 1;
        src = fc1w + (blk * 16 + lr) * 64 + half * 32 + lhi * 8;
    } else {                         // fc2_w [64][256]
        int f = frag - 64; int pair = f >> 1, half = f & 1;
        int k = pair >> 2, nt = pair & 3;
        src = fc2w + (nt * 16 + lr) * 256 + k * 64 + half * 32 + lhi * 8;
    }
    float4 v0 = *(const float4*)src;
    float4 v1 = *(const float4*)(src + 4);
    s16x8 o = { f2s(v0.x), f2s(v0.y), f2s(v0.z), f2s(v0.w),
                f2s(v1.x), f2s(v1.y), f2s(v1.z), f2s(v1.w) };
    *(s16x8*)&wb[frag * 512 + l * 8] = o;
}

// ---------------------------------------------------------------------------
// Kernel 1: conv embed 3x3, CIN=3 -> ED=64, NCHW f32 in -> NHWC bf16 out.
// ---------------------------------------------------------------------------
__global__ __launch_bounds__(256) void k_conv_embed(
    const float* __restrict__ x, const float* __restrict__ we,
    const float* __restrict__ be, bf16* __restrict__ xe)
{
    const int t    = threadIdx.x;
    const int wv   = t >> 6;
    const int lane = t & 63;
    const int hb   = blockIdx.x;          // b*256 + h
    const int h    = hb & 255;
    const int b    = hb >> 8;
    const int col  = wv * 64 + lane;

    const float* xb = x + (size_t)b * (CIN_ * H_ * W_);

    float xr[27];
#pragma unroll
    for (int ci = 0; ci < 3; ++ci)
#pragma unroll
        for (int kh = 0; kh < 3; ++kh) {
            int hy = h + kh - 1;
#pragma unroll
            for (int kw = 0; kw < 3; ++kw) {
                int wx = col + kw - 1;
                bool ok = ((unsigned)hy < 256u) & ((unsigned)wx < 256u);
                xr[ci * 9 + kh * 3 + kw] = ok ? xb[ci * 65536 + hy * 256 + wx] : 0.f;
            }
        }

    unsigned pk[32];
#pragma unroll 4
    for (int op = 0; op < 32; ++op) {
        float a0 = be[2 * op];
        float a1 = be[2 * op + 1];
        const float* w0 = we + (2 * op) * 27;
#pragma unroll
        for (int k = 0; k < 27; ++k) {
            a0 += xr[k] * w0[k];
            a1 += xr[k] * w0[27 + k];
        }
        pk[op] = pack2(a0, a1);
    }

    size_t pixel = (size_t)hb * 256 + col;
    uint4* dst = (uint4*)((short*)xe + pixel * 64);
#pragma unroll
    for (int i = 0; i < 8; ++i) dst[i] = *(uint4*)&pk[i * 4];
}

// ---------------------------------------------------------------------------
// Kernel 2: FUSED shifted-window attention + MLP. One block per window.
// attn stages 1-5 as before; x_out kept in LDS (s_x) + registers (val),
// then LN2 + fc1 + GELU + fc2 + residual, reusing dead LDS buffers
// (xn->s_q, h->s_k). All mlp LDS traffic is wave-private rows -> no new
// barriers (kernel keeps attn's 3). xf stored with window-reverse+roll.
// ---------------------------------------------------------------------------
__global__ __launch_bounds__(256, 3) void k_attn_mlp(
    const bf16* __restrict__ xe, const short* __restrict__ wq,
    const float* __restrict__ qkv_b, const short* __restrict__ wp,
    const float* __restrict__ proj_b, const float* __restrict__ n1_g,
    const float* __restrict__ n1_b, const short* __restrict__ w1,
    const float* __restrict__ fc1_b, const short* __restrict__ w2,
    const float* __restrict__ fc2_b, const float* __restrict__ n2_g,
    const float* __restrict__ n2_b, bf16* __restrict__ xf)
{
    __shared__ short s_x[64 * 64];     // Xn; then O; then x_out (val)
    __shared__ short s_q[64 * 64];     // Q; then xn (post-LN2)
    __shared__ short s_k[64 * 64];     // K; then h (fc1+GELU out)
    __shared__ short s_vt[64 * 64];    // V^T [d][tok]

    const int t    = threadIdx.x;
    const int w    = t >> 6;
    const int lane = t & 63;
    const int lr   = lane & 15;
    const int lhi  = lane >> 4;

    const int bi  = blockIdx.x;
    const int b   = bi >> 10;
    const int wh  = (bi >> 5) & 31;
    const int wwi = bi & 31;
    const int eh  = (wh == 31), ew = (wwi == 31);

    const bf16* xeb = xe + (size_t)b * (H_ * W_ * ED_);
    const f32x4 cz = { 0.f, 0.f, 0.f, 0.f };

    // ---- stage 1: token load (rolled) + LN1 -> s_x ----
    {
        int n = t >> 2, q = t & 3;
        int hp = (wh * 8 + (n >> 3) + 4) & 255;
        int wp_ = (wwi * 8 + (n & 7) + 4) & 255;
        const short* src = (const short*)xeb + (hp * 256 + wp_) * 64 + q * 16;
        s16x8 u0 = *(const s16x8*)src;
        s16x8 u1 = *(const s16x8*)(src + 8);
        float v[16];
        float s = 0.f, sq = 0.f;
#pragma unroll
        for (int j = 0; j < 8; ++j) { v[j] = s2f(u0[j]); v[8 + j] = s2f(u1[j]); }
#pragma unroll
        for (int j = 0; j < 16; ++j) { s += v[j]; sq += v[j] * v[j]; }
        s  += __shfl_xor(s, 1);  s  += __shfl_xor(s, 2);
        sq += __shfl_xor(sq, 1); sq += __shfl_xor(sq, 2);
        float m = s * (1.f / 64.f);
        float rstd = rsqrtf(sq * (1.f / 64.f) - m * m + EPS_);
        s16x8 w0, w1_;
#pragma unroll
        for (int j = 0; j < 8; ++j) {
            w0[j]  = f2s((v[j] - m) * rstd * n1_g[q * 16 + j] + n1_b[q * 16 + j]);
            w1_[j] = f2s((v[8 + j] - m) * rstd * n1_g[q * 16 + 8 + j] + n1_b[q * 16 + 8 + j]);
        }
        *(s16x8*)&s_x[lbase(n, q * 16)]     = w0;
        *(s16x8*)&s_x[lbase(n, q * 16 + 8)] = w1_;
    }
    __syncthreads();

    // ---- stage 2: QKV GEMMs ----
    {
        int arow = w * 16 + lr;
        s16x8 a0 = ld8(&s_x[lbase(arow, lhi * 8)]);
        s16x8 a1 = ld8(&s_x[lbase(arow, 32 + lhi * 8)]);
#pragma unroll
        for (int nt = 0; nt < 8; ++nt) {        // Q: nt 0..3, K: nt 4..7
            s16x8 b0 = *(const s16x8*)&wq[(nt * 2 + 0) * 512 + lane * 8];
            s16x8 b1 = *(const s16x8*)&wq[(nt * 2 + 1) * 512 + lane * 8];
            f32x4 c = mfma16(a1, b1, mfma16(a0, b0, cz));
            float bias = qkv_b[nt * 16 + lr];
#pragma unroll
            for (int r = 0; r < 4; ++r) {
                int tok = w * 16 + lhi * 4 + r;
                float val = c[r] + bias;
                if (nt < 4) { val *= 0.25f; s_q[lswz(tok, nt * 16 + lr)] = f2s(val); }
                else        {               s_k[lswz(tok, (nt - 4) * 16 + lr)] = f2s(val); }
            }
        }
        // V^T: A = Wv fragment block (8 + w)
        s16x8 av0 = *(const s16x8*)&wq[((8 + w) * 2 + 0) * 512 + lane * 8];
        s16x8 av1 = *(const s16x8*)&wq[((8 + w) * 2 + 1) * 512 + lane * 8];
#pragma unroll
        for (int nt = 0; nt < 4; ++nt) {
            s16x8 b0 = ld8(&s_x[lbase(nt * 16 + lr, lhi * 8)]);
            s16x8 b1 = ld8(&s_x[lbase(nt * 16 + lr, 32 + lhi * 8)]);
            f32x4 c = mfma16(av1, b1, mfma16(av0, b0, cz));
#pragma unroll
            for (int r = 0; r < 4; ++r) {
                int d = w * 16 + lhi * 4 + r;
                s_vt[lswz(d, nt * 16 + lr)] = f2s(c[r] + qkv_b[128 + d]);
            }
        }
    }
    __syncthreads();

    // ---- stage 3: S^T = K Q^T per head + softmax -> packed P in registers ----
    const int h = w;
    uint2 pk[4][4];
    {
        const s16x8 z8 = { 0, 0, 0, 0, 0, 0, 0, 0 };
        s16x8 kb[4];
#pragma unroll
        for (int mt = 0; mt < 4; ++mt)
            kb[mt] = (lhi >= 2) ? z8
                   : ld8(&s_k[lbase(mt * 16 + lr, h * 16 + (lhi & 1) * 8)]);
#pragma unroll
        for (int nt = 0; nt < 4; ++nt) {
            s16x8 qb = ld8(&s_q[lbase(nt * 16 + lr, h * 16 + (lhi & 1) * 8)]);
            f32x4 S[4];
#pragma unroll
            for (int mt = 0; mt < 4; ++mt)
                S[mt] = mfma16(kb[mt], qb, cz);

            if (eh | ew) {
                int qc = clsf(nt * 16 + lr, eh, ew);
#pragma unroll
                for (int mt = 0; mt < 4; ++mt)
#pragma unroll
                    for (int r = 0; r < 4; ++r) {
                        int kc = clsf(mt * 16 + lhi * 4 + r, eh, ew);
                        S[mt][r] += (kc != qc) ? -100.f : 0.f;
                    }
            }
            float mx = -1e30f;
#pragma unroll
            for (int mt = 0; mt < 4; ++mt)
#pragma unroll
                for (int r = 0; r < 4; ++r) mx = fmaxf(mx, S[mt][r]);
            mx = fmaxf(mx, __shfl_xor(mx, 16));
            mx = fmaxf(mx, __shfl_xor(mx, 32));
            float ev[4][4];
            float sm = 0.f;
#pragma unroll
            for (int mt = 0; mt < 4; ++mt)
#pragma unroll
                for (int r = 0; r < 4; ++r) {
                    ev[mt][r] = __expf(S[mt][r] - mx);
                    sm += ev[mt][r];
                }
            sm += __shfl_xor(sm, 16);
            sm += __shfl_xor(sm, 32);
            float inv = frcp(sm);
#pragma unroll
            for (int mt = 0; mt < 4; ++mt) {
                pk[nt][mt].x = pack2(ev[mt][0] * inv, ev[mt][1] * inv);
                pk[nt][mt].y = pack2(ev[mt][2] * inv, ev[mt][3] * inv);
            }
        }
    }

    // ---- stage 4: O = P V ; P A-fragments built by intra-wave shuffles ----
    {
        f32x4 O[4] = { cz, cz, cz, cz };
        const int  srcl2 = lr + 32 * (lhi & 1);
        const bool selhi = (lhi >= 2);
#pragma unroll
        for (int ks = 0; ks < 2; ++ks) {
            s16x8 bv = ld8(&s_vt[lbase(h * 16 + lr, ks * 32 + lhi * 8)]);
#pragma unroll
            for (int mo = 0; mo < 4; ++mo) {
                unsigned lAx = (unsigned)__shfl((int)pk[mo][ks * 2 + 0].x, srcl2);
                unsigned lAy = (unsigned)__shfl((int)pk[mo][ks * 2 + 0].y, srcl2);
                unsigned lBx = (unsigned)__shfl((int)pk[mo][ks * 2 + 1].x, srcl2);
                unsigned lBy = (unsigned)__shfl((int)pk[mo][ks * 2 + 1].y, srcl2);
                unsigned hAx = (unsigned)__shfl((int)pk[mo][ks * 2 + 0].x, srcl2 + 16);
                unsigned hAy = (unsigned)__shfl((int)pk[mo][ks * 2 + 0].y, srcl2 + 16);
                unsigned hBx = (unsigned)__shfl((int)pk[mo][ks * 2 + 1].x, srcl2 + 16);
                unsigned hBy = (unsigned)__shfl((int)pk[mo][ks * 2 + 1].y, srcl2 + 16);
                uint4 pa;
                pa.x = selhi ? lBx : lAx;
                pa.y = selhi ? lBy : lAy;
                pa.z = selhi ? hBx : hAx;
                pa.w = selhi ? hBy : hAy;
                O[mo] = mfma16(*(s16x8*)&pa, bv, O[mo]);
            }
        }
        // store O -> s_x overlay (Xn dead since stage-2 barrier)
#pragma unroll
        for (int mo = 0; mo < 4; ++mo)
#pragma unroll
            for (int r = 0; r < 4; ++r)
                s_x[lswz(mo * 16 + lhi * 4 + r, h * 16 + lr)] = f2s(O[mo][r]);
    }
    __syncthreads();

    // ---- stage 5: proj + residual -> x_out in registers (val) + s_x ----
    size_t rowbase[4];
    float  valr[4][4];                 // x_out[token=w*16+lhi*4+r][chan=nt*16+lr]
    {
        int arow = w * 16 + lr;
        s16x8 a0 = ld8(&s_x[lbase(arow, lhi * 8)]);
        s16x8 a1 = ld8(&s_x[lbase(arow, 32 + lhi * 8)]);
#pragma unroll
        for (int r = 0; r < 4; ++r) {
            int tok = w * 16 + lhi * 4 + r;
            int hp = (wh * 8 + (tok >> 3) + 4) & 255;
            int wpx = (wwi * 8 + (tok & 7) + 4) & 255;
            rowbase[r] = (size_t)(hp * 256 + wpx) * 64;
        }
#pragma unroll
        for (int nt = 0; nt < 4; ++nt) {
            s16x8 b0 = *(const s16x8*)&wp[(nt * 2 + 0) * 512 + lane * 8];
            s16x8 b1 = *(const s16x8*)&wp[(nt * 2 + 1) * 512 + lane * 8];
            f32x4 c = mfma16(a1, b1, mfma16(a0, b0, cz));
            float bias = proj_b[nt * 16 + lr];
#pragma unroll
            for (int r = 0; r < 4; ++r) {
                int tok = w * 16 + lhi * 4 + r;
                short vs = f2s(c[r] + bias + b2f(xeb[rowbase[r] + nt * 16 + lr]));
                s_x[lswz(tok, nt * 16 + lr)] = vs;   // wave-private rows
                valr[nt][r] = s2f(vs);               // residual for mlp epilogue
            }
        }
    }
    // no barrier needed: all following LDS traffic is wave-private rows,
    // and same-wave DS ops execute in program order.

    // ---- stage 6: LN2 (from s_x) -> xn in s_q ----
    {
        int n = w * 16 + (lane >> 2), q = lane & 3;
        s16x8 u0 = ld8(&s_x[lbase(n, q * 16)]);
        s16x8 u1 = ld8(&s_x[lbase(n, q * 16 + 8)]);
        float v[16];
        float s = 0.f, sq = 0.f;
#pragma unroll
        for (int j = 0; j < 8; ++j) { v[j] = s2f(u0[j]); v[8 + j] = s2f(u1[j]); }
#pragma unroll
        for (int j = 0; j < 16; ++j) { s += v[j]; sq += v[j] * v[j]; }
        s  += __shfl_xor(s, 1);  s  += __shfl_xor(s, 2);
        sq += __shfl_xor(sq, 1); sq += __shfl_xor(sq, 2);
        float m = s * (1.f / 64.f);
        float rstd = rsqrtf(sq * (1.f / 64.f) - m * m + EPS_);
        s16x8 w0, w1_;
#pragma unroll
        for (int j = 0; j < 8; ++j) {
            w0[j]  = f2s((v[j] - m) * rstd * n2_g[q * 16 + j] + n2_b[q * 16 + j]);
            w1_[j] = f2s((v[8 + j] - m) * rstd * n2_g[q * 16 + 8 + j] + n2_b[q * 16 + 8 + j]);
        }
        *(s16x8*)&s_q[lbase(n, q * 16)]     = w0;
        *(s16x8*)&s_q[lbase(n, q * 16 + 8)] = w1_;
    }

    // ---- stage 7: fc1 + tanh-GELU (h -> s_k) + fc2 accumulate ----
    f32x4 acc[4] = { cz, cz, cz, cz };
    {
        const int arow = w * 16 + lr;
        s16x8 xa0 = ld8(&s_q[lbase(arow, lhi * 8)]);
        s16x8 xa1 = ld8(&s_q[lbase(arow, 32 + lhi * 8)]);

        for (int k = 0; k < 4; ++k) {
#pragma unroll
            for (int nt = 0; nt < 4; ++nt) {
                const short* bp = &w1[((k * 4 + nt) * 2) * 512 + lane * 8];
                s16x8 b0 = *(const s16x8*)bp;
                s16x8 b1 = *(const s16x8*)(bp + 512);
                f32x4 c = mfma16(xa1, b1, mfma16(xa0, b0, cz));
                float bias = fc1_b[k * 64 + nt * 16 + lr];
#pragma unroll
                for (int r = 0; r < 4; ++r) {
                    float hv = c[r] + bias;
                    float u = hv + 0.044715f * hv * hv * hv;
                    hv = hv * frcp(1.f + __expf(-1.5957691216f * u));
                    s_k[lswz(w * 16 + lhi * 4 + r, nt * 16 + lr)] = f2s(hv);
                }
            }
            s16x8 h0 = ld8(&s_k[lbase(arow, lhi * 8)]);
            s16x8 h1 = ld8(&s_k[lbase(arow, 32 + lhi * 8)]);
#pragma unroll
            for (int nt = 0; nt < 4; ++nt) {
                const short* bp2 = &w2[((k * 4 + nt) * 2) * 512 + lane * 8];
                s16x8 b0 = *(const s16x8*)bp2;
                s16x8 b1 = *(const s16x8*)(bp2 + 512);
                acc[nt] = mfma16(h1, b1, mfma16(h0, b0, acc[nt]));
            }
        }
    }

    // ---- stage 8: bias + residual(val) + store xf (window-reverse + roll) ----
    {
        const size_t bbase = (size_t)b * (H_ * W_ * ED_);
        short* xfs = (short*)xf;
#pragma unroll
        for (int nt = 0; nt < 4; ++nt) {
            float bias = fc2_b[nt * 16 + lr];
#pragma unroll
            for (int r = 0; r < 4; ++r) {
                size_t gi = bbase + rowbase[r] + nt * 16 + lr;
                xfs[gi] = f2s(acc[nt][r] + bias + valr[nt][r]);
            }
        }
    }
}

// ---------------------------------------------------------------------------
// Kernel 3: conv up 3x3, ED=64 -> CIN=3, MFMA GEMM.
// ---------------------------------------------------------------------------
__global__ __launch_bounds__(256) void k_conv_up(
    const float* __restrict__ x, const bf16* __restrict__ xf,
    const float* __restrict__ wu, const float* __restrict__ bu,
    float* __restrict__ out)
{
    __shared__ short s_t[198 * 64];    // xf tile [kh*66 + wx_local][ci], swizzled
    __shared__ short s_bf[1152 * 8];   // B-fragments [(tap*2+half)*64 + lane][8]
    __shared__ float s_wu[1728];       // wu fp32 staging

    const int t    = threadIdx.x;
    const int pix0 = blockIdx.x * 64;
    const int b    = pix0 >> 16;
    const int h    = (pix0 >> 8) & 255;
    const int w0   = pix0 & 255;

    const short* xfs = (const short*)xf;

    for (int e = t; e < 1584; e += 256) {
        int rc = e >> 3, j8 = e & 7;
        int hy_l = (unsigned)rc / 66u;
        int wx_l = rc - hy_l * 66;
        int hy = h + hy_l - 1;
        int wx = w0 + wx_l - 1;
        s16x8 v = { 0, 0, 0, 0, 0, 0, 0, 0 };
        if (((unsigned)hy < 256u) & ((unsigned)wx < 256u))
            v = *(const s16x8*)&xfs[((size_t)((b * 256 + hy) * 256 + wx)) * 64 + j8 * 8];
        *(s16x8*)&s_t[lbase(rc, j8 * 8)] = v;
    }
    for (int e = t; e < 1728; e += 256) s_wu[e] = wu[e];
    __syncthreads();

    for (int fid = t; fid < 1152; fid += 256) {
        int tap  = fid >> 7;
        int half = (fid >> 6) & 1;
        int ln   = fid & 63;
        int co   = ln & 15;
        s16x8 v = { 0, 0, 0, 0, 0, 0, 0, 0 };
        if (co < 3) {
            int ci0 = half * 32 + (ln >> 4) * 8;
#pragma unroll
            for (int j = 0; j < 8; ++j)
                v[j] = f2s(s_wu[(co * 64 + ci0 + j) * 9 + tap]);
        }
        *(s16x8*)&s_bf[fid * 8] = v;
    }
    __syncthreads();

    const int wv   = t >> 6;
    const int lane = t & 63;
    const int lr   = lane & 15;
    const int lhi  = lane >> 4;

    f32x4 acc = { 0.f, 0.f, 0.f, 0.f };
#pragma unroll
    for (int kh = 0; kh < 3; ++kh)
#pragma unroll
        for (int kw = 0; kw < 3; ++kw) {
            const int tap = kh * 3 + kw;
            const int R   = kh * 66 + wv * 16 + lr + kw;
#pragma unroll
            for (int half = 0; half < 2; ++half) {
                s16x8 a   = ld8(&s_t[lbase(R, half * 32 + lhi * 8)]);
                s16x8 bfr = ld8(&s_bf[((tap * 2 + half) * 64 + lane) * 8]);
                acc = mfma16(a, bfr, acc);
            }
        }

    if (lr < 3) {
        const int co = lr;
        const int wp = wv * 16 + lhi * 4;
        size_t o0 = (size_t)b * 3 * 65536 + (size_t)co * 65536 + (size_t)h * 256 + w0 + wp;
        float4 xv = *(const float4*)&x[o0];
        float bias = bu[co];
        float4 ov;
        ov.x = acc[0] + bias + xv.x;
        ov.y = acc[1] + bias + xv.y;
        ov.z = acc[2] + bias + xv.z;
        ov.w = acc[3] + bias + xv.w;
        *(float4*)&out[o0] = ov;
    }
}

// ---------------------------------------------------------------------------
extern "C" void kernel_launch(void* const* d_in, const int* in_sizes, int n_in,
                              void* d_out, int out_size, void* d_ws, size_t ws_size,
                              hipStream_t stream)
{
    const float* x     = (const float*)d_in[0];
    const float* cew   = (const float*)d_in[1];
    const float* ceb   = (const float*)d_in[2];
    const float* n1g   = (const float*)d_in[3];
    const float* n1b   = (const float*)d_in[4];
    const float* qkvw  = (const float*)d_in[5];
    const float* qkvb  = (const float*)d_in[6];
    const float* projw = (const float*)d_in[7];
    const float* projb = (const float*)d_in[8];
    const float* n2g   = (const float*)d_in[9];
    const float* n2b   = (const float*)d_in[10];
    const float* fc1w  = (const float*)d_in[11];
    const float* fc1b  = (const float*)d_in[12];
    const float* fc2w  = (const float*)d_in[13];
    const float* fc2b  = (const float*)d_in[14];
    const float* cuw   = (const float*)d_in[15];
    const float* cub   = (const float*)d_in[16];
    float* out = (float*)d_out;

    const size_t planeElems = (size_t)B_ * H_ * W_ * ED_;   // 33.5M
    bf16* xe = (bf16*)d_ws;
    bf16* xf = (bf16*)((char*)d_ws + planeElems * sizeof(bf16));

    // Fragment-layout bf16 weights live in d_out head (read by attn_mlp only;
    // conv_up fully overwrites d_out at the end of the launch).
    short* wb = (short*)d_out;

    hipLaunchKernelGGL(k_prep, dim3(NFRAG * 64 / 256), dim3(256), 0, stream,
                       qkvw, projw, fc1w, fc2w, wb);
    hipLaunchKernelGGL(k_conv_embed, dim3(2048), dim3(256), 0, stream, x, cew, ceb, xe);
    hipLaunchKernelGGL(k_attn_mlp,   dim3(8192), dim3(256), 0, stream,
                       xe, wb + WQ_OFF, qkvb, wb + WP_OFF, projb, n1g, n1b,
                       wb + W1_OFF, fc1b, wb + W2_OFF, fc2b, n2g, n2b, xf);
    hipLaunchKernelGGL(k_conv_up,    dim3(8192), dim3(256), 0, stream, x, xf, cuw, cub, out);
}

// Round 12
// 396.882 us; speedup vs baseline: 1.6420x; 1.0222x over previous
//
#include <hip/hip_runtime.h>
#include <hip/hip_bf16.h>
#include <math.h>

using bf16 = __hip_bfloat16;

typedef short s16x8 __attribute__((ext_vector_type(8)));
typedef short s16x4 __attribute__((ext_vector_type(4)));
typedef float f32x4 __attribute__((ext_vector_type(4)));

static __device__ __forceinline__ float s2f(short s) {
    return __uint_as_float(((unsigned)(unsigned short)s) << 16);
}
static __device__ __forceinline__ short f2s(float v) {
    bf16 b = __float2bfloat16(v);
    return *reinterpret_cast<short*>(&b);
}
static __device__ __forceinline__ float b2f(bf16 v) { return __bfloat162float(v); }
static __device__ __forceinline__ bf16  f2b(float v) { return __float2bfloat16(v); }
static __device__ __forceinline__ unsigned pack2(float a, float b) {
    return (unsigned)(unsigned short)f2s(a) | ((unsigned)(unsigned short)f2s(b) << 16);
}
static __device__ __forceinline__ float frcp(float x) {
    return __builtin_amdgcn_rcpf(x);
}

// 64-col bf16 LDS tile, XOR-swizzled 16B blocks
static __device__ __forceinline__ int lswz(int row, int col) {
    return row * 64 + ((((col >> 3) ^ row) & 7) << 3) + (col & 7);
}
static __device__ __forceinline__ int lbase(int row, int col) {
    return row * 64 + ((((col >> 3) ^ row) & 7) << 3);
}
static __device__ __forceinline__ s16x8 ld8(const short* p) {
    return *(const s16x8*)p;
}
static __device__ __forceinline__ f32x4 mfma16(s16x8 a, s16x8 b, f32x4 c) {
    return __builtin_amdgcn_mfma_f32_16x16x32_bf16(a, b, c, 0, 0, 0);
}

constexpr int B_   = 8;
constexpr int CIN_ = 3;
constexpr int H_   = 256;
constexpr int W_   = 256;
constexpr int ED_  = 64;
constexpr float EPS_ = 1e-5f;

// Fragment-layout weight scratch (elements, inside d_out head).
constexpr int WQ_OFF  = 0;       // qkv  frags  0..23
constexpr int WP_OFF  = 12288;   // proj frags 24..31
constexpr int W1_OFF  = 16384;   // fc1  frags 32..63
constexpr int W2_OFF  = 32768;   // fc2  frags 64..95
constexpr int NFRAG   = 96;

// region class for shifted-window mask (SHIFT=4, WS=8)
static __device__ __forceinline__ int clsf(int tok, int eh, int ew) {
    int ch = eh ? (1 + ((tok >> 3) >= 4)) : 0;
    int cw = ew ? (1 + ((tok & 7) >= 4)) : 0;
    return ch * 3 + cw;
}

// ---------------------------------------------------------------------------
// Kernel 0: weights fp32 -> bf16 MFMA-fragment layout.
// ---------------------------------------------------------------------------
__global__ __launch_bounds__(256) void k_prep(
    const float* __restrict__ qkvw, const float* __restrict__ projw,
    const float* __restrict__ fc1w, const float* __restrict__ fc2w,
    short* __restrict__ wb)
{
    int g    = blockIdx.x * 256 + threadIdx.x;   // 0..6143
    int l    = g & 63;
    int frag = g >> 6;                           // 0..95
    int lr   = l & 15, lhi = l >> 4;

    const float* src;
    if (frag < 24) {                 // qkv_w [192][64]
        int blk = frag >> 1, half = frag & 1;
        src = qkvw + (blk * 16 + lr) * 64 + half * 32 + lhi * 8;
    } else if (frag < 32) {          // proj_w [64][64]
        int f = frag - 24; int blk = f >> 1, half = f & 1;
        src = projw + (blk * 16 + lr) * 64 + half * 32 + lhi * 8;
    } else if (frag < 64) {          // fc1_w [256][64]
        int f = frag - 32; int blk = f >> 1, half = f & 1;
        src = fc1w + (blk * 16 + lr) * 64 + half * 32 + lhi * 8;
    } else {                         // fc2_w [64][256]
        int f = frag - 64; int pair = f >> 1, half = f & 1;
        int k = pair >> 2, nt = pair & 3;
        src = fc2w + (nt * 16 + lr) * 256 + k * 64 + half * 32 + lhi * 8;
    }
    float4 v0 = *(const float4*)src;
    float4 v1 = *(const float4*)(src + 4);
    s16x8 o = { f2s(v0.x), f2s(v0.y), f2s(v0.z), f2s(v0.w),
                f2s(v1.x), f2s(v1.y), f2s(v1.z), f2s(v1.w) };
    *(s16x8*)&wb[frag * 512 + l * 8] = o;
}

// ---------------------------------------------------------------------------
// Kernel 1: conv embed 3x3, CIN=3 -> ED=64, NCHW f32 in -> NHWC bf16 out.
// ---------------------------------------------------------------------------
__global__ __launch_bounds__(256) void k_conv_embed(
    const float* __restrict__ x, const float* __restrict__ we,
    const float* __restrict__ be, bf16* __restrict__ xe)
{
    const int t    = threadIdx.x;
    const int wv   = t >> 6;
    const int lane = t & 63;
    const int hb   = blockIdx.x;          // b*256 + h
    const int h    = hb & 255;
    const int b    = hb >> 8;
    const int col  = wv * 64 + lane;

    const float* xb = x + (size_t)b * (CIN_ * H_ * W_);

    float xr[27];
#pragma unroll
    for (int ci = 0; ci < 3; ++ci)
#pragma unroll
        for (int kh = 0; kh < 3; ++kh) {
            int hy = h + kh - 1;
#pragma unroll
            for (int kw = 0; kw < 3; ++kw) {
                int wx = col + kw - 1;
                bool ok = ((unsigned)hy < 256u) & ((unsigned)wx < 256u);
                xr[ci * 9 + kh * 3 + kw] = ok ? xb[ci * 65536 + hy * 256 + wx] : 0.f;
            }
        }

    unsigned pk[32];
#pragma unroll 4
    for (int op = 0; op < 32; ++op) {
        float a0 = be[2 * op];
        float a1 = be[2 * op + 1];
        const float* w0 = we + (2 * op) * 27;
#pragma unroll
        for (int k = 0; k < 27; ++k) {
            a0 += xr[k] * w0[k];
            a1 += xr[k] * w0[27 + k];
        }
        pk[op] = pack2(a0, a1);
    }

    size_t pixel = (size_t)hb * 256 + col;
    uint4* dst = (uint4*)((short*)xe + pixel * 64);
#pragma unroll
    for (int i = 0; i < 8; ++i) dst[i] = *(uint4*)&pk[i * 4];
}

// ---------------------------------------------------------------------------
// Kernel 2: FUSED shifted-window attention + MLP. One block per window.
// LN2 fully in registers (shuffle-reduce over 16-lane groups) -> no
// bank-conflicting LDS reads (R11: 4.45M conflicts from the old stage-6).
// ---------------------------------------------------------------------------
__global__ __launch_bounds__(256, 4) void k_attn_mlp(
    const bf16* __restrict__ xe, const short* __restrict__ wq,
    const float* __restrict__ qkv_b, const short* __restrict__ wp,
    const float* __restrict__ proj_b, const float* __restrict__ n1_g,
    const float* __restrict__ n1_b, const short* __restrict__ w1,
    const float* __restrict__ fc1_b, const short* __restrict__ w2,
    const float* __restrict__ fc2_b, const float* __restrict__ n2_g,
    const float* __restrict__ n2_b, bf16* __restrict__ xf)
{
    __shared__ short s_x[64 * 64];     // Xn; then O; then x_out
    __shared__ short s_q[64 * 64];     // Q
    __shared__ short s_k[64 * 64];     // K; then h (fc1+GELU out)
    __shared__ short s_vt[64 * 64];    // V^T [d][tok]

    const int t    = threadIdx.x;
    const int w    = t >> 6;
    const int lane = t & 63;
    const int lr   = lane & 15;
    const int lhi  = lane >> 4;

    const int bi  = blockIdx.x;
    const int b   = bi >> 10;
    const int wh  = (bi >> 5) & 31;
    const int wwi = bi & 31;
    const int eh  = (wh == 31), ew = (wwi == 31);

    const bf16* xeb = xe + (size_t)b * (H_ * W_ * ED_);
    const f32x4 cz = { 0.f, 0.f, 0.f, 0.f };

    // ---- stage 1: token load (rolled) + LN1 -> s_x ----
    {
        int n = t >> 2, q = t & 3;
        int hp = (wh * 8 + (n >> 3) + 4) & 255;
        int wp_ = (wwi * 8 + (n & 7) + 4) & 255;
        const short* src = (const short*)xeb + (hp * 256 + wp_) * 64 + q * 16;
        s16x8 u0 = *(const s16x8*)src;
        s16x8 u1 = *(const s16x8*)(src + 8);
        float v[16];
        float s = 0.f, sq = 0.f;
#pragma unroll
        for (int j = 0; j < 8; ++j) { v[j] = s2f(u0[j]); v[8 + j] = s2f(u1[j]); }
#pragma unroll
        for (int j = 0; j < 16; ++j) { s += v[j]; sq += v[j] * v[j]; }
        s  += __shfl_xor(s, 1);  s  += __shfl_xor(s, 2);
        sq += __shfl_xor(sq, 1); sq += __shfl_xor(sq, 2);
        float m = s * (1.f / 64.f);
        float rstd = rsqrtf(sq * (1.f / 64.f) - m * m + EPS_);
        s16x8 w0, w1_;
#pragma unroll
        for (int j = 0; j < 8; ++j) {
            w0[j]  = f2s((v[j] - m) * rstd * n1_g[q * 16 + j] + n1_b[q * 16 + j]);
            w1_[j] = f2s((v[8 + j] - m) * rstd * n1_g[q * 16 + 8 + j] + n1_b[q * 16 + 8 + j]);
        }
        *(s16x8*)&s_x[lbase(n, q * 16)]     = w0;
        *(s16x8*)&s_x[lbase(n, q * 16 + 8)] = w1_;
    }
    __syncthreads();

    // ---- stage 2: QKV GEMMs ----
    {
        int arow = w * 16 + lr;
        s16x8 a0 = ld8(&s_x[lbase(arow, lhi * 8)]);
        s16x8 a1 = ld8(&s_x[lbase(arow, 32 + lhi * 8)]);
#pragma unroll
        for (int nt = 0; nt < 8; ++nt) {        // Q: nt 0..3, K: nt 4..7
            s16x8 b0 = *(const s16x8*)&wq[(nt * 2 + 0) * 512 + lane * 8];
            s16x8 b1 = *(const s16x8*)&wq[(nt * 2 + 1) * 512 + lane * 8];
            f32x4 c = mfma16(a1, b1, mfma16(a0, b0, cz));
            float bias = qkv_b[nt * 16 + lr];
#pragma unroll
            for (int r = 0; r < 4; ++r) {
                int tok = w * 16 + lhi * 4 + r;
                float val = c[r] + bias;
                if (nt < 4) { val *= 0.25f; s_q[lswz(tok, nt * 16 + lr)] = f2s(val); }
                else        {               s_k[lswz(tok, (nt - 4) * 16 + lr)] = f2s(val); }
            }
        }
        // V^T: A = Wv fragment block (8 + w)
        s16x8 av0 = *(const s16x8*)&wq[((8 + w) * 2 + 0) * 512 + lane * 8];
        s16x8 av1 = *(const s16x8*)&wq[((8 + w) * 2 + 1) * 512 + lane * 8];
#pragma unroll
        for (int nt = 0; nt < 4; ++nt) {
            s16x8 b0 = ld8(&s_x[lbase(nt * 16 + lr, lhi * 8)]);
            s16x8 b1 = ld8(&s_x[lbase(nt * 16 + lr, 32 + lhi * 8)]);
            f32x4 c = mfma16(av1, b1, mfma16(av0, b0, cz));
#pragma unroll
            for (int r = 0; r < 4; ++r) {
                int d = w * 16 + lhi * 4 + r;
                s_vt[lswz(d, nt * 16 + lr)] = f2s(c[r] + qkv_b[128 + d]);
            }
        }
    }
    __syncthreads();

    // ---- stage 3: S^T = K Q^T per head + softmax -> packed P in registers ----
    const int h = w;
    uint2 pk[4][4];
    {
        const s16x8 z8 = { 0, 0, 0, 0, 0, 0, 0, 0 };
        s16x8 kb[4];
#pragma unroll
        for (int mt = 0; mt < 4; ++mt)
            kb[mt] = (lhi >= 2) ? z8
                   : ld8(&s_k[lbase(mt * 16 + lr, h * 16 + (lhi & 1) * 8)]);
#pragma unroll
        for (int nt = 0; nt < 4; ++nt) {
            s16x8 qb = ld8(&s_q[lbase(nt * 16 + lr, h * 16 + (lhi & 1) * 8)]);
            f32x4 S[4];
#pragma unroll
            for (int mt = 0; mt < 4; ++mt)
                S[mt] = mfma16(kb[mt], qb, cz);

            if (eh | ew) {
                int qc = clsf(nt * 16 + lr, eh, ew);
#pragma unroll
                for (int mt = 0; mt < 4; ++mt)
#pragma unroll
                    for (int r = 0; r < 4; ++r) {
                        int kc = clsf(mt * 16 + lhi * 4 + r, eh, ew);
                        S[mt][r] += (kc != qc) ? -100.f : 0.f;
                    }
            }
            float mx = -1e30f;
#pragma unroll
            for (int mt = 0; mt < 4; ++mt)
#pragma unroll
                for (int r = 0; r < 4; ++r) mx = fmaxf(mx, S[mt][r]);
            mx = fmaxf(mx, __shfl_xor(mx, 16));
            mx = fmaxf(mx, __shfl_xor(mx, 32));
            float ev[4][4];
            float sm = 0.f;
#pragma unroll
            for (int mt = 0; mt < 4; ++mt)
#pragma unroll
                for (int r = 0; r < 4; ++r) {
                    ev[mt][r] = __expf(S[mt][r] - mx);
                    sm += ev[mt][r];
                }
            sm += __shfl_xor(sm, 16);
            sm += __shfl_xor(sm, 32);
            float inv = frcp(sm);
#pragma unroll
            for (int mt = 0; mt < 4; ++mt) {
                pk[nt][mt].x = pack2(ev[mt][0] * inv, ev[mt][1] * inv);
                pk[nt][mt].y = pack2(ev[mt][2] * inv, ev[mt][3] * inv);
            }
        }
    }

    // ---- stage 4: O = P V ; P A-fragments built by intra-wave shuffles ----
    {
        f32x4 O[4] = { cz, cz, cz, cz };
        const int  srcl2 = lr + 32 * (lhi & 1);
        const bool selhi = (lhi >= 2);
#pragma unroll
        for (int ks = 0; ks < 2; ++ks) {
            s16x8 bv = ld8(&s_vt[lbase(h * 16 + lr, ks * 32 + lhi * 8)]);
#pragma unroll
            for (int mo = 0; mo < 4; ++mo) {
                unsigned lAx = (unsigned)__shfl((int)pk[mo][ks * 2 + 0].x, srcl2);
                unsigned lAy = (unsigned)__shfl((int)pk[mo][ks * 2 + 0].y, srcl2);
                unsigned lBx = (unsigned)__shfl((int)pk[mo][ks * 2 + 1].x, srcl2);
                unsigned lBy = (unsigned)__shfl((int)pk[mo][ks * 2 + 1].y, srcl2);
                unsigned hAx = (unsigned)__shfl((int)pk[mo][ks * 2 + 0].x, srcl2 + 16);
                unsigned hAy = (unsigned)__shfl((int)pk[mo][ks * 2 + 0].y, srcl2 + 16);
                unsigned hBx = (unsigned)__shfl((int)pk[mo][ks * 2 + 1].x, srcl2 + 16);
                unsigned hBy = (unsigned)__shfl((int)pk[mo][ks * 2 + 1].y, srcl2 + 16);
                uint4 pa;
                pa.x = selhi ? lBx : lAx;
                pa.y = selhi ? lBy : lAy;
                pa.z = selhi ? hBx : hAx;
                pa.w = selhi ? hBy : hAy;
                O[mo] = mfma16(*(s16x8*)&pa, bv, O[mo]);
            }
        }
        // store O -> s_x overlay (Xn dead since stage-2 barrier)
#pragma unroll
        for (int mo = 0; mo < 4; ++mo)
#pragma unroll
            for (int r = 0; r < 4; ++r)
                s_x[lswz(mo * 16 + lhi * 4 + r, h * 16 + lr)] = f2s(O[mo][r]);
    }
    __syncthreads();

    // ---- stage 5: proj + residual -> x_out (s_x rows, wave-private) + valr ----
    size_t rowbase[4];
    float  valr[4][4];                 // x_out[token=w*16+lhi*4+r][chan=nt*16+lr]
    {
        int arow = w * 16 + lr;
        s16x8 a0 = ld8(&s_x[lbase(arow, lhi * 8)]);
        s16x8 a1 = ld8(&s_x[lbase(arow, 32 + lhi * 8)]);
#pragma unroll
        for (int r = 0; r < 4; ++r) {
            int tok = w * 16 + lhi * 4 + r;
            int hp = (wh * 8 + (tok >> 3) + 4) & 255;
            int wpx = (wwi * 8 + (tok & 7) + 4) & 255;
            rowbase[r] = (size_t)(hp * 256 + wpx) * 64;
        }
#pragma unroll
        for (int nt = 0; nt < 4; ++nt) {
            s16x8 b0 = *(const s16x8*)&wp[(nt * 2 + 0) * 512 + lane * 8];
            s16x8 b1 = *(const s16x8*)&wp[(nt * 2 + 1) * 512 + lane * 8];
            f32x4 c = mfma16(a1, b1, mfma16(a0, b0, cz));
            float bias = proj_b[nt * 16 + lr];
#pragma unroll
            for (int r = 0; r < 4; ++r) {
                int tok = w * 16 + lhi * 4 + r;
                short vs = f2s(c[r] + bias + b2f(xeb[rowbase[r] + nt * 16 + lr]));
                s_x[lswz(tok, nt * 16 + lr)] = vs;   // wave-private rows
                valr[nt][r] = s2f(vs);               // residual for mlp epilogue
            }
        }
    }
    // no barrier needed: all following LDS traffic is wave-private rows,
    // and same-wave DS ops execute in program order.

    // ---- stage 6: LN2 stats fully in registers (16-lane-group reduce) ----
    float mean4[4], rstd4[4];
    {
        float ls[4], lq[4];
#pragma unroll
        for (int r = 0; r < 4; ++r) {
            ls[r] = valr[0][r] + valr[1][r] + valr[2][r] + valr[3][r];
            lq[r] = valr[0][r] * valr[0][r] + valr[1][r] * valr[1][r]
                  + valr[2][r] * valr[2][r] + valr[3][r] * valr[3][r];
        }
#pragma unroll
        for (int m = 1; m < 16; m <<= 1) {
#pragma unroll
            for (int r = 0; r < 4; ++r) {
                ls[r] += __shfl_xor(ls[r], m);
                lq[r] += __shfl_xor(lq[r], m);
            }
        }
#pragma unroll
        for (int r = 0; r < 4; ++r) {
            float mn = ls[r] * (1.f / 64.f);
            mean4[r] = mn;
            rstd4[r] = rsqrtf(lq[r] * (1.f / 64.f) - mn * mn + EPS_);
        }
    }

    // ---- stage 7: build xn A-fragments in registers; fc1+GELU+fc2 ----
    f32x4 acc[4] = { cz, cz, cz, cz };
    {
        const int arow = w * 16 + lr;
        // fetch stats for token arow (held by lane group lr>>2, slot lr&3)
        const int srcl = (lr >> 2) * 16;
        float m0 = __shfl(mean4[0], srcl), m1 = __shfl(mean4[1], srcl);
        float m2 = __shfl(mean4[2], srcl), m3 = __shfl(mean4[3], srcl);
        float s0 = __shfl(rstd4[0], srcl), s1 = __shfl(rstd4[1], srcl);
        float s2v = __shfl(rstd4[2], srcl), s3 = __shfl(rstd4[3], srcl);
        const int rp = lr & 3;
        float meanT = (rp & 2) ? ((rp & 1) ? m3 : m2) : ((rp & 1) ? m1 : m0);
        float rstdT = (rp & 2) ? ((rp & 1) ? s3 : s2v) : ((rp & 1) ? s1 : s0);

        s16x8 ra0 = ld8(&s_x[lbase(arow, lhi * 8)]);
        s16x8 ra1 = ld8(&s_x[lbase(arow, 32 + lhi * 8)]);
        s16x8 xa0, xa1;
#pragma unroll
        for (int j = 0; j < 8; ++j) {
            float g0 = n2_g[lhi * 8 + j],      bb0 = n2_b[lhi * 8 + j];
            float g1 = n2_g[32 + lhi * 8 + j], bb1 = n2_b[32 + lhi * 8 + j];
            xa0[j] = f2s((s2f(ra0[j]) - meanT) * rstdT * g0 + bb0);
            xa1[j] = f2s((s2f(ra1[j]) - meanT) * rstdT * g1 + bb1);
        }

        for (int k = 0; k < 4; ++k) {
#pragma unroll
            for (int nt = 0; nt < 4; ++nt) {
                const short* bp = &w1[((k * 4 + nt) * 2) * 512 + lane * 8];
                s16x8 b0 = *(const s16x8*)bp;
                s16x8 b1 = *(const s16x8*)(bp + 512);
                f32x4 c = mfma16(xa1, b1, mfma16(xa0, b0, cz));
                float bias = fc1_b[k * 64 + nt * 16 + lr];
#pragma unroll
                for (int r = 0; r < 4; ++r) {
                    float hv = c[r] + bias;
                    float u = hv + 0.044715f * hv * hv * hv;
                    hv = hv * frcp(1.f + __expf(-1.5957691216f * u));
                    s_k[lswz(w * 16 + lhi * 4 + r, nt * 16 + lr)] = f2s(hv);
                }
            }
            s16x8 h0 = ld8(&s_k[lbase(arow, lhi * 8)]);
            s16x8 h1 = ld8(&s_k[lbase(arow, 32 + lhi * 8)]);
#pragma unroll
            for (int nt = 0; nt < 4; ++nt) {
                const short* bp2 = &w2[((k * 4 + nt) * 2) * 512 + lane * 8];
                s16x8 b0 = *(const s16x8*)bp2;
                s16x8 b1 = *(const s16x8*)(bp2 + 512);
                acc[nt] = mfma16(h1, b1, mfma16(h0, b0, acc[nt]));
            }
        }
    }

    // ---- stage 8: bias + residual(valr) + store xf (window-reverse + roll) ----
    {
        const size_t bbase = (size_t)b * (H_ * W_ * ED_);
        short* xfs = (short*)xf;
#pragma unroll
        for (int nt = 0; nt < 4; ++nt) {
            float bias = fc2_b[nt * 16 + lr];
#pragma unroll
            for (int r = 0; r < 4; ++r) {
                size_t gi = bbase + rowbase[r] + nt * 16 + lr;
                xfs[gi] = f2s(acc[nt][r] + bias + valr[nt][r]);
            }
        }
    }
}

// ---------------------------------------------------------------------------
// Kernel 3: conv up 3x3, ED=64 -> CIN=3, MFMA GEMM.
// ---------------------------------------------------------------------------
__global__ __launch_bounds__(256) void k_conv_up(
    const float* __restrict__ x, const bf16* __restrict__ xf,
    const float* __restrict__ wu, const float* __restrict__ bu,
    float* __restrict__ out)
{
    __shared__ short s_t[198 * 64];    // xf tile [kh*66 + wx_local][ci], swizzled
    __shared__ short s_bf[1152 * 8];   // B-fragments [(tap*2+half)*64 + lane][8]
    __shared__ float s_wu[1728];       // wu fp32 staging

    const int t    = threadIdx.x;
    const int pix0 = blockIdx.x * 64;
    const int b    = pix0 >> 16;
    const int h    = (pix0 >> 8) & 255;
    const int w0   = pix0 & 255;

    const short* xfs = (const short*)xf;

    for (int e = t; e < 1584; e += 256) {
        int rc = e >> 3, j8 = e & 7;
        int hy_l = (unsigned)rc / 66u;
        int wx_l = rc - hy_l * 66;
        int hy = h + hy_l - 1;
        int wx = w0 + wx_l - 1;
        s16x8 v = { 0, 0, 0, 0, 0, 0, 0, 0 };
        if (((unsigned)hy < 256u) & ((unsigned)wx < 256u))
            v = *(const s16x8*)&xfs[((size_t)((b * 256 + hy) * 256 + wx)) * 64 + j8 * 8];
        *(s16x8*)&s_t[lbase(rc, j8 * 8)] = v;
    }
    for (int e = t; e < 1728; e += 256) s_wu[e] = wu[e];
    __syncthreads();

    for (int fid = t; fid < 1152; fid += 256) {
        int tap  = fid >> 7;
        int half = (fid >> 6) & 1;
        int ln   = fid & 63;
        int co   = ln & 15;
        s16x8 v = { 0, 0, 0, 0, 0, 0, 0, 0 };
        if (co < 3) {
            int ci0 = half * 32 + (ln >> 4) * 8;
#pragma unroll
            for (int j = 0; j < 8; ++j)
                v[j] = f2s(s_wu[(co * 64 + ci0 + j) * 9 + tap]);
        }
        *(s16x8*)&s_bf[fid * 8] = v;
    }
    __syncthreads();

    const int wv   = t >> 6;
    const int lane = t & 63;
    const int lr   = lane & 15;
    const int lhi  = lane >> 4;

    f32x4 acc = { 0.f, 0.f, 0.f, 0.f };
#pragma unroll
    for (int kh = 0; kh < 3; ++kh)
#pragma unroll
        for (int kw = 0; kw < 3; ++kw) {
            const int tap = kh * 3 + kw;
            const int R   = kh * 66 + wv * 16 + lr + kw;
#pragma unroll
            for (int half = 0; half < 2; ++half) {
                s16x8 a   = ld8(&s_t[lbase(R, half * 32 + lhi * 8)]);
                s16x8 bfr = ld8(&s_bf[((tap * 2 + half) * 64 + lane) * 8]);
                acc = mfma16(a, bfr, acc);
            }
        }

    if (lr < 3) {
        const int co = lr;
        const int wp = wv * 16 + lhi * 4;
        size_t o0 = (size_t)b * 3 * 65536 + (size_t)co * 65536 + (size_t)h * 256 + w0 + wp;
        float4 xv = *(const float4*)&x[o0];
        float bias = bu[co];
        float4 ov;
        ov.x = acc[0] + bias + xv.x;
        ov.y = acc[1] + bias + xv.y;
        ov.z = acc[2] + bias + xv.z;
        ov.w = acc[3] + bias + xv.w;
        *(float4*)&out[o0] = ov;
    }
}

// ---------------------------------------------------------------------------
extern "C" void kernel_launch(void* const* d_in, const int* in_sizes, int n_in,
                              void* d_out, int out_size, void* d_ws, size_t ws_size,
                              hipStream_t stream)
{
    const float* x     = (const float*)d_in[0];
    const float* cew   = (const float*)d_in[1];
    const float* ceb   = (const float*)d_in[2];
    const float* n1g   = (const float*)d_in[3];
    const float* n1b   = (const float*)d_in[4];
    const float* qkvw  = (const float*)d_in[5];
    const float* qkvb  = (const float*)d_in[6];
    const float* projw = (const float*)d_in[7];
    const float* projb = (const float*)d_in[8];
    const float* n2g   = (const float*)d_in[9];
    const float* n2b   = (const float*)d_in[10];
    const float* fc1w  = (const float*)d_in[11];
    const float* fc1b  = (const float*)d_in[12];
    const float* fc2w  = (const float*)d_in[13];
    const float* fc2b  = (const float*)d_in[14];
    const float* cuw   = (const float*)d_in[15];
    const float* cub   = (const float*)d_in[16];
    float* out = (float*)d_out;

    const size_t planeElems = (size_t)B_ * H_ * W_ * ED_;   // 33.5M
    bf16* xe = (bf16*)d_ws;
    bf16* xf = (bf16*)((char*)d_ws + planeElems * sizeof(bf16));

    // Fragment-layout bf16 weights live in d_out head (read by attn_mlp only;
    // conv_up fully overwrites d_out at the end of the launch).
    short* wb = (short*)d_out;

    hipLaunchKernelGGL(k_prep, dim3(NFRAG * 64 / 256), dim3(256), 0, stream,
                       qkvw, projw, fc1w, fc2w, wb);
    hipLaunchKernelGGL(k_conv_embed, dim3(2048), dim3(256), 0, stream, x, cew, ceb, xe);
    hipLaunchKernelGGL(k_attn_mlp,   dim3(8192), dim3(256), 0, stream,
                       xe, wb + WQ_OFF, qkvb, wb + WP_OFF, projb, n1g, n1b,
                       wb + W1_OFF, fc1b, wb + W2_OFF, fc2b, n2g, n2b, xf);
    hipLaunchKernelGGL(k_conv_up,    dim3(8192), dim3(256), 0, stream, x, xf, cuw, cub, out);
}

// Round 13
// 391.576 us; speedup vs baseline: 1.6643x; 1.0135x over previous
//
#include <hip/hip_runtime.h>
#include <hip/hip_bf16.h>
#include <math.h>

using bf16 = __hip_bfloat16;

typedef short s16x8 __attribute__((ext_vector_type(8)));
typedef short s16x4 __attribute__((ext_vector_type(4)));
typedef float f32x4 __attribute__((ext_vector_type(4)));

static __device__ __forceinline__ float s2f(short s) {
    return __uint_as_float(((unsigned)(unsigned short)s) << 16);
}
static __device__ __forceinline__ short f2s(float v) {
    bf16 b = __float2bfloat16(v);
    return *reinterpret_cast<short*>(&b);
}
static __device__ __forceinline__ float b2f(bf16 v) { return __bfloat162float(v); }
static __device__ __forceinline__ bf16  f2b(float v) { return __float2bfloat16(v); }
static __device__ __forceinline__ unsigned pack2(float a, float b) {
    return (unsigned)(unsigned short)f2s(a) | ((unsigned)(unsigned short)f2s(b) << 16);
}
static __device__ __forceinline__ float frcp(float x) {
    return __builtin_amdgcn_rcpf(x);
}

// 64-col bf16 LDS tile, XOR-swizzled 16B blocks
static __device__ __forceinline__ int lswz(int row, int col) {
    return row * 64 + ((((col >> 3) ^ row) & 7) << 3) + (col & 7);
}
static __device__ __forceinline__ int lbase(int row, int col) {
    return row * 64 + ((((col >> 3) ^ row) & 7) << 3);
}
static __device__ __forceinline__ s16x8 ld8(const short* p) {
    return *(const s16x8*)p;
}
static __device__ __forceinline__ f32x4 mfma16(s16x8 a, s16x8 b, f32x4 c) {
    return __builtin_amdgcn_mfma_f32_16x16x32_bf16(a, b, c, 0, 0, 0);
}

constexpr int B_   = 8;
constexpr int CIN_ = 3;
constexpr int H_   = 256;
constexpr int W_   = 256;
constexpr int ED_  = 64;
constexpr float EPS_ = 1e-5f;

// Fragment-layout weight scratch (elements, inside d_out head).
constexpr int WQ_OFF  = 0;       // qkv  frags  0..23
constexpr int WP_OFF  = 12288;   // proj frags 24..31
constexpr int W1_OFF  = 16384;   // fc1  frags 32..63
constexpr int W2_OFF  = 32768;   // fc2  frags 64..95
constexpr int NFRAG   = 96;

// region class for shifted-window mask (SHIFT=4, WS=8)
static __device__ __forceinline__ int clsf(int tok, int eh, int ew) {
    int ch = eh ? (1 + ((tok >> 3) >= 4)) : 0;
    int cw = ew ? (1 + ((tok & 7) >= 4)) : 0;
    return ch * 3 + cw;
}

// ---------------------------------------------------------------------------
// Kernel 0: weights fp32 -> bf16 MFMA-fragment layout.
// ---------------------------------------------------------------------------
__global__ __launch_bounds__(256) void k_prep(
    const float* __restrict__ qkvw, const float* __restrict__ projw,
    const float* __restrict__ fc1w, const float* __restrict__ fc2w,
    short* __restrict__ wb)
{
    int g    = blockIdx.x * 256 + threadIdx.x;   // 0..6143
    int l    = g & 63;
    int frag = g >> 6;                           // 0..95
    int lr   = l & 15, lhi = l >> 4;

    const float* src;
    if (frag < 24) {                 // qkv_w [192][64]
        int blk = frag >> 1, half = frag & 1;
        src = qkvw + (blk * 16 + lr) * 64 + half * 32 + lhi * 8;
    } else if (frag < 32) {          // proj_w [64][64]
        int f = frag - 24; int blk = f >> 1, half = f & 1;
        src = projw + (blk * 16 + lr) * 64 + half * 32 + lhi * 8;
    } else if (frag < 64) {          // fc1_w [256][64]
        int f = frag - 32; int blk = f >> 1, half = f & 1;
        src = fc1w + (blk * 16 + lr) * 64 + half * 32 + lhi * 8;
    } else {                         // fc2_w [64][256]
        int f = frag - 64; int pair = f >> 1, half = f & 1;
        int k = pair >> 2, nt = pair & 3;
        src = fc2w + (nt * 16 + lr) * 256 + k * 64 + half * 32 + lhi * 8;
    }
    float4 v0 = *(const float4*)src;
    float4 v1 = *(const float4*)(src + 4);
    s16x8 o = { f2s(v0.x), f2s(v0.y), f2s(v0.z), f2s(v0.w),
                f2s(v1.x), f2s(v1.y), f2s(v1.z), f2s(v1.w) };
    *(s16x8*)&wb[frag * 512 + l * 8] = o;
}

// ---------------------------------------------------------------------------
// Kernel 1: conv embed 3x3, CIN=3 -> ED=64, NCHW f32 in -> NHWC bf16 out.
// ---------------------------------------------------------------------------
__global__ __launch_bounds__(256) void k_conv_embed(
    const float* __restrict__ x, const float* __restrict__ we,
    const float* __restrict__ be, bf16* __restrict__ xe)
{
    const int t    = threadIdx.x;
    const int wv   = t >> 6;
    const int lane = t & 63;
    const int hb   = blockIdx.x;          // b*256 + h
    const int h    = hb & 255;
    const int b    = hb >> 8;
    const int col  = wv * 64 + lane;

    const float* xb = x + (size_t)b * (CIN_ * H_ * W_);

    float xr[27];
#pragma unroll
    for (int ci = 0; ci < 3; ++ci)
#pragma unroll
        for (int kh = 0; kh < 3; ++kh) {
            int hy = h + kh - 1;
#pragma unroll
            for (int kw = 0; kw < 3; ++kw) {
                int wx = col + kw - 1;
                bool ok = ((unsigned)hy < 256u) & ((unsigned)wx < 256u);
                xr[ci * 9 + kh * 3 + kw] = ok ? xb[ci * 65536 + hy * 256 + wx] : 0.f;
            }
        }

    unsigned pk[32];
#pragma unroll 4
    for (int op = 0; op < 32; ++op) {
        float a0 = be[2 * op];
        float a1 = be[2 * op + 1];
        const float* w0 = we + (2 * op) * 27;
#pragma unroll
        for (int k = 0; k < 27; ++k) {
            a0 += xr[k] * w0[k];
            a1 += xr[k] * w0[27 + k];
        }
        pk[op] = pack2(a0, a1);
    }

    size_t pixel = (size_t)hb * 256 + col;
    uint4* dst = (uint4*)((short*)xe + pixel * 64);
#pragma unroll
    for (int i = 0; i < 8; ++i) dst[i] = *(uint4*)&pk[i * 4];
}

// ---------------------------------------------------------------------------
// Kernel 2: FUSED shifted-window attention + MLP. One block per window.
// waves_per_eu pinned to (4,4): R12's min-only bound made the allocator
// chase 8 waves/EU (64 VGPR + 27MB scratch spill) that LDS caps anyway.
// ---------------------------------------------------------------------------
__global__ __launch_bounds__(256)
__attribute__((amdgpu_waves_per_eu(4, 4)))
void k_attn_mlp(
    const bf16* __restrict__ xe, const short* __restrict__ wq,
    const float* __restrict__ qkv_b, const short* __restrict__ wp,
    const float* __restrict__ proj_b, const float* __restrict__ n1_g,
    const float* __restrict__ n1_b, const short* __restrict__ w1,
    const float* __restrict__ fc1_b, const short* __restrict__ w2,
    const float* __restrict__ fc2_b, const float* __restrict__ n2_g,
    const float* __restrict__ n2_b, bf16* __restrict__ xf)
{
    __shared__ short s_x[64 * 64];     // Xn; then O; then x_out
    __shared__ short s_q[64 * 64];     // Q
    __shared__ short s_k[64 * 64];     // K; then h (fc1+GELU out)
    __shared__ short s_vt[64 * 64];    // V^T [d][tok]

    const int t    = threadIdx.x;
    const int w    = t >> 6;
    const int lane = t & 63;
    const int lr   = lane & 15;
    const int lhi  = lane >> 4;

    const int bi  = blockIdx.x;
    const int b   = bi >> 10;
    const int wh  = (bi >> 5) & 31;
    const int wwi = bi & 31;
    const int eh  = (wh == 31), ew = (wwi == 31);

    const bf16* xeb = xe + (size_t)b * (H_ * W_ * ED_);
    const f32x4 cz = { 0.f, 0.f, 0.f, 0.f };

    // ---- stage 1: token load (rolled) + LN1 -> s_x ----
    {
        int n = t >> 2, q = t & 3;
        int hp = (wh * 8 + (n >> 3) + 4) & 255;
        int wp_ = (wwi * 8 + (n & 7) + 4) & 255;
        const short* src = (const short*)xeb + (hp * 256 + wp_) * 64 + q * 16;
        s16x8 u0 = *(const s16x8*)src;
        s16x8 u1 = *(const s16x8*)(src + 8);
        float v[16];
        float s = 0.f, sq = 0.f;
#pragma unroll
        for (int j = 0; j < 8; ++j) { v[j] = s2f(u0[j]); v[8 + j] = s2f(u1[j]); }
#pragma unroll
        for (int j = 0; j < 16; ++j) { s += v[j]; sq += v[j] * v[j]; }
        s  += __shfl_xor(s, 1);  s  += __shfl_xor(s, 2);
        sq += __shfl_xor(sq, 1); sq += __shfl_xor(sq, 2);
        float m = s * (1.f / 64.f);
        float rstd = rsqrtf(sq * (1.f / 64.f) - m * m + EPS_);
        s16x8 w0, w1_;
#pragma unroll
        for (int j = 0; j < 8; ++j) {
            w0[j]  = f2s((v[j] - m) * rstd * n1_g[q * 16 + j] + n1_b[q * 16 + j]);
            w1_[j] = f2s((v[8 + j] - m) * rstd * n1_g[q * 16 + 8 + j] + n1_b[q * 16 + 8 + j]);
        }
        *(s16x8*)&s_x[lbase(n, q * 16)]     = w0;
        *(s16x8*)&s_x[lbase(n, q * 16 + 8)] = w1_;
    }
    __syncthreads();

    // ---- stage 2: QKV GEMMs ----
    {
        int arow = w * 16 + lr;
        s16x8 a0 = ld8(&s_x[lbase(arow, lhi * 8)]);
        s16x8 a1 = ld8(&s_x[lbase(arow, 32 + lhi * 8)]);
#pragma unroll
        for (int nt = 0; nt < 8; ++nt) {        // Q: nt 0..3, K: nt 4..7
            s16x8 b0 = *(const s16x8*)&wq[(nt * 2 + 0) * 512 + lane * 8];
            s16x8 b1 = *(const s16x8*)&wq[(nt * 2 + 1) * 512 + lane * 8];
            f32x4 c = mfma16(a1, b1, mfma16(a0, b0, cz));
            float bias = qkv_b[nt * 16 + lr];
#pragma unroll
            for (int r = 0; r < 4; ++r) {
                int tok = w * 16 + lhi * 4 + r;
                float val = c[r] + bias;
                if (nt < 4) { val *= 0.25f; s_q[lswz(tok, nt * 16 + lr)] = f2s(val); }
                else        {               s_k[lswz(tok, (nt - 4) * 16 + lr)] = f2s(val); }
            }
        }
        // V^T: A = Wv fragment block (8 + w)
        s16x8 av0 = *(const s16x8*)&wq[((8 + w) * 2 + 0) * 512 + lane * 8];
        s16x8 av1 = *(const s16x8*)&wq[((8 + w) * 2 + 1) * 512 + lane * 8];
#pragma unroll
        for (int nt = 0; nt < 4; ++nt) {
            s16x8 b0 = ld8(&s_x[lbase(nt * 16 + lr, lhi * 8)]);
            s16x8 b1 = ld8(&s_x[lbase(nt * 16 + lr, 32 + lhi * 8)]);
            f32x4 c = mfma16(av1, b1, mfma16(av0, b0, cz));
#pragma unroll
            for (int r = 0; r < 4; ++r) {
                int d = w * 16 + lhi * 4 + r;
                s_vt[lswz(d, nt * 16 + lr)] = f2s(c[r] + qkv_b[128 + d]);
            }
        }
    }
    __syncthreads();

    // ---- stage 3: S^T = K Q^T per head + softmax -> packed P in registers ----
    const int h = w;
    uint2 pk[4][4];
    {
        const s16x8 z8 = { 0, 0, 0, 0, 0, 0, 0, 0 };
        s16x8 kb[4];
#pragma unroll
        for (int mt = 0; mt < 4; ++mt)
            kb[mt] = (lhi >= 2) ? z8
                   : ld8(&s_k[lbase(mt * 16 + lr, h * 16 + (lhi & 1) * 8)]);
#pragma unroll
        for (int nt = 0; nt < 4; ++nt) {
            s16x8 qb = ld8(&s_q[lbase(nt * 16 + lr, h * 16 + (lhi & 1) * 8)]);
            f32x4 S[4];
#pragma unroll
            for (int mt = 0; mt < 4; ++mt)
                S[mt] = mfma16(kb[mt], qb, cz);

            if (eh | ew) {
                int qc = clsf(nt * 16 + lr, eh, ew);
#pragma unroll
                for (int mt = 0; mt < 4; ++mt)
#pragma unroll
                    for (int r = 0; r < 4; ++r) {
                        int kc = clsf(mt * 16 + lhi * 4 + r, eh, ew);
                        S[mt][r] += (kc != qc) ? -100.f : 0.f;
                    }
            }
            float mx = -1e30f;
#pragma unroll
            for (int mt = 0; mt < 4; ++mt)
#pragma unroll
                for (int r = 0; r < 4; ++r) mx = fmaxf(mx, S[mt][r]);
            mx = fmaxf(mx, __shfl_xor(mx, 16));
            mx = fmaxf(mx, __shfl_xor(mx, 32));
            float ev[4][4];
            float sm = 0.f;
#pragma unroll
            for (int mt = 0; mt < 4; ++mt)
#pragma unroll
                for (int r = 0; r < 4; ++r) {
                    ev[mt][r] = __expf(S[mt][r] - mx);
                    sm += ev[mt][r];
                }
            sm += __shfl_xor(sm, 16);
            sm += __shfl_xor(sm, 32);
            float inv = frcp(sm);
#pragma unroll
            for (int mt = 0; mt < 4; ++mt) {
                pk[nt][mt].x = pack2(ev[mt][0] * inv, ev[mt][1] * inv);
                pk[nt][mt].y = pack2(ev[mt][2] * inv, ev[mt][3] * inv);
            }
        }
    }

    // ---- stage 4: O = P V ; P A-fragments built by intra-wave shuffles ----
    {
        f32x4 O[4] = { cz, cz, cz, cz };
        const int  srcl2 = lr + 32 * (lhi & 1);
        const bool selhi = (lhi >= 2);
#pragma unroll
        for (int ks = 0; ks < 2; ++ks) {
            s16x8 bv = ld8(&s_vt[lbase(h * 16 + lr, ks * 32 + lhi * 8)]);
#pragma unroll
            for (int mo = 0; mo < 4; ++mo) {
                unsigned lAx = (unsigned)__shfl((int)pk[mo][ks * 2 + 0].x, srcl2);
                unsigned lAy = (unsigned)__shfl((int)pk[mo][ks * 2 + 0].y, srcl2);
                unsigned lBx = (unsigned)__shfl((int)pk[mo][ks * 2 + 1].x, srcl2);
                unsigned lBy = (unsigned)__shfl((int)pk[mo][ks * 2 + 1].y, srcl2);
                unsigned hAx = (unsigned)__shfl((int)pk[mo][ks * 2 + 0].x, srcl2 + 16);
                unsigned hAy = (unsigned)__shfl((int)pk[mo][ks * 2 + 0].y, srcl2 + 16);
                unsigned hBx = (unsigned)__shfl((int)pk[mo][ks * 2 + 1].x, srcl2 + 16);
                unsigned hBy = (unsigned)__shfl((int)pk[mo][ks * 2 + 1].y, srcl2 + 16);
                uint4 pa;
                pa.x = selhi ? lBx : lAx;
                pa.y = selhi ? lBy : lAy;
                pa.z = selhi ? hBx : hAx;
                pa.w = selhi ? hBy : hAy;
                O[mo] = mfma16(*(s16x8*)&pa, bv, O[mo]);
            }
        }
        // store O -> s_x overlay (Xn dead since stage-2 barrier)
#pragma unroll
        for (int mo = 0; mo < 4; ++mo)
#pragma unroll
            for (int r = 0; r < 4; ++r)
                s_x[lswz(mo * 16 + lhi * 4 + r, h * 16 + lr)] = f2s(O[mo][r]);
    }
    __syncthreads();

    // ---- stage 5: proj + residual -> x_out (s_x rows, wave-private) + valr ----
    size_t rowbase[4];
    float  valr[4][4];                 // x_out[token=w*16+lhi*4+r][chan=nt*16+lr]
    {
        int arow = w * 16 + lr;
        s16x8 a0 = ld8(&s_x[lbase(arow, lhi * 8)]);
        s16x8 a1 = ld8(&s_x[lbase(arow, 32 + lhi * 8)]);
#pragma unroll
        for (int r = 0; r < 4; ++r) {
            int tok = w * 16 + lhi * 4 + r;
            int hp = (wh * 8 + (tok >> 3) + 4) & 255;
            int wpx = (wwi * 8 + (tok & 7) + 4) & 255;
            rowbase[r] = (size_t)(hp * 256 + wpx) * 64;
        }
#pragma unroll
        for (int nt = 0; nt < 4; ++nt) {
            s16x8 b0 = *(const s16x8*)&wp[(nt * 2 + 0) * 512 + lane * 8];
            s16x8 b1 = *(const s16x8*)&wp[(nt * 2 + 1) * 512 + lane * 8];
            f32x4 c = mfma16(a1, b1, mfma16(a0, b0, cz));
            float bias = proj_b[nt * 16 + lr];
#pragma unroll
            for (int r = 0; r < 4; ++r) {
                int tok = w * 16 + lhi * 4 + r;
                short vs = f2s(c[r] + bias + b2f(xeb[rowbase[r] + nt * 16 + lr]));
                s_x[lswz(tok, nt * 16 + lr)] = vs;   // wave-private rows
                valr[nt][r] = s2f(vs);               // residual for mlp epilogue
            }
        }
    }
    // no barrier needed: all following LDS traffic is wave-private rows,
    // and same-wave DS ops execute in program order.

    // ---- stage 6: LN2 stats fully in registers (16-lane-group reduce) ----
    float mean4[4], rstd4[4];
    {
        float ls[4], lq[4];
#pragma unroll
        for (int r = 0; r < 4; ++r) {
            ls[r] = valr[0][r] + valr[1][r] + valr[2][r] + valr[3][r];
            lq[r] = valr[0][r] * valr[0][r] + valr[1][r] * valr[1][r]
                  + valr[2][r] * valr[2][r] + valr[3][r] * valr[3][r];
        }
#pragma unroll
        for (int m = 1; m < 16; m <<= 1) {
#pragma unroll
            for (int r = 0; r < 4; ++r) {
                ls[r] += __shfl_xor(ls[r], m);
                lq[r] += __shfl_xor(lq[r], m);
            }
        }
#pragma unroll
        for (int r = 0; r < 4; ++r) {
            float mn = ls[r] * (1.f / 64.f);
            mean4[r] = mn;
            rstd4[r] = rsqrtf(lq[r] * (1.f / 64.f) - mn * mn + EPS_);
        }
    }

    // ---- stage 7: build xn A-fragments in registers; fc1+GELU+fc2 ----
    f32x4 acc[4] = { cz, cz, cz, cz };
    {
        const int arow = w * 16 + lr;
        // fetch stats for token arow (held by lane group lr>>2, slot lr&3)
        const int srcl = (lr >> 2) * 16;
        float m0 = __shfl(mean4[0], srcl), m1 = __shfl(mean4[1], srcl);
        float m2 = __shfl(mean4[2], srcl), m3 = __shfl(mean4[3], srcl);
        float s0 = __shfl(rstd4[0], srcl), s1 = __shfl(rstd4[1], srcl);
        float s2v = __shfl(rstd4[2], srcl), s3 = __shfl(rstd4[3], srcl);
        const int rp = lr & 3;
        float meanT = (rp & 2) ? ((rp & 1) ? m3 : m2) : ((rp & 1) ? m1 : m0);
        float rstdT = (rp & 2) ? ((rp & 1) ? s3 : s2v) : ((rp & 1) ? s1 : s0);

        s16x8 ra0 = ld8(&s_x[lbase(arow, lhi * 8)]);
        s16x8 ra1 = ld8(&s_x[lbase(arow, 32 + lhi * 8)]);
        s16x8 xa0, xa1;
#pragma unroll
        for (int j = 0; j < 8; ++j) {
            float g0 = n2_g[lhi * 8 + j],      bb0 = n2_b[lhi * 8 + j];
            float g1 = n2_g[32 + lhi * 8 + j], bb1 = n2_b[32 + lhi * 8 + j];
            xa0[j] = f2s((s2f(ra0[j]) - meanT) * rstdT * g0 + bb0);
            xa1[j] = f2s((s2f(ra1[j]) - meanT) * rstdT * g1 + bb1);
        }

        for (int k = 0; k < 4; ++k) {
#pragma unroll
            for (int nt = 0; nt < 4; ++nt) {
                const short* bp = &w1[((k * 4 + nt) * 2) * 512 + lane * 8];
                s16x8 b0 = *(const s16x8*)bp;
                s16x8 b1 = *(const s16x8*)(bp + 512);
                f32x4 c = mfma16(xa1, b1, mfma16(xa0, b0, cz));
                float bias = fc1_b[k * 64 + nt * 16 + lr];
#pragma unroll
                for (int r = 0; r < 4; ++r) {
                    float hv = c[r] + bias;
                    float u = hv + 0.044715f * hv * hv * hv;
                    hv = hv * frcp(1.f + __expf(-1.5957691216f * u));
                    s_k[lswz(w * 16 + lhi * 4 + r, nt * 16 + lr)] = f2s(hv);
                }
            }
            s16x8 h0 = ld8(&s_k[lbase(arow, lhi * 8)]);
            s16x8 h1 = ld8(&s_k[lbase(arow, 32 + lhi * 8)]);
#pragma unroll
            for (int nt = 0; nt < 4; ++nt) {
                const short* bp2 = &w2[((k * 4 + nt) * 2) * 512 + lane * 8];
                s16x8 b0 = *(const s16x8*)bp2;
                s16x8 b1 = *(const s16x8*)(bp2 + 512);
                acc[nt] = mfma16(h1, b1, mfma16(h0, b0, acc[nt]));
            }
        }
    }

    // ---- stage 8: bias + residual(valr) + store xf (window-reverse + roll) ----
    {
        const size_t bbase = (size_t)b * (H_ * W_ * ED_);
        short* xfs = (short*)xf;
#pragma unroll
        for (int nt = 0; nt < 4; ++nt) {
            float bias = fc2_b[nt * 16 + lr];
#pragma unroll
            for (int r = 0; r < 4; ++r) {
                size_t gi = bbase + rowbase[r] + nt * 16 + lr;
                xfs[gi] = f2s(acc[nt][r] + bias + valr[nt][r]);
            }
        }
    }
}

// ---------------------------------------------------------------------------
// Kernel 3: conv up 3x3, ED=64 -> CIN=3, MFMA GEMM.
// ---------------------------------------------------------------------------
__global__ __launch_bounds__(256) void k_conv_up(
    const float* __restrict__ x, const bf16* __restrict__ xf,
    const float* __restrict__ wu, const float* __restrict__ bu,
    float* __restrict__ out)
{
    __shared__ short s_t[198 * 64];    // xf tile [kh*66 + wx_local][ci], swizzled
    __shared__ short s_bf[1152 * 8];   // B-fragments [(tap*2+half)*64 + lane][8]
    __shared__ float s_wu[1728];       // wu fp32 staging

    const int t    = threadIdx.x;
    const int pix0 = blockIdx.x * 64;
    const int b    = pix0 >> 16;
    const int h    = (pix0 >> 8) & 255;
    const int w0   = pix0 & 255;

    const short* xfs = (const short*)xf;

    for (int e = t; e < 1584; e += 256) {
        int rc = e >> 3, j8 = e & 7;
        int hy_l = (unsigned)rc / 66u;
        int wx_l = rc - hy_l * 66;
        int hy = h + hy_l - 1;
        int wx = w0 + wx_l - 1;
        s16x8 v = { 0, 0, 0, 0, 0, 0, 0, 0 };
        if (((unsigned)hy < 256u) & ((unsigned)wx < 256u))
            v = *(const s16x8*)&xfs[((size_t)((b * 256 + hy) * 256 + wx)) * 64 + j8 * 8];
        *(s16x8*)&s_t[lbase(rc, j8 * 8)] = v;
    }
    for (int e = t; e < 1728; e += 256) s_wu[e] = wu[e];
    __syncthreads();

    for (int fid = t; fid < 1152; fid += 256) {
        int tap  = fid >> 7;
        int half = (fid >> 6) & 1;
        int ln   = fid & 63;
        int co   = ln & 15;
        s16x8 v = { 0, 0, 0, 0, 0, 0, 0, 0 };
        if (co < 3) {
            int ci0 = half * 32 + (ln >> 4) * 8;
#pragma unroll
            for (int j = 0; j < 8; ++j)
                v[j] = f2s(s_wu[(co * 64 + ci0 + j) * 9 + tap]);
        }
        *(s16x8*)&s_bf[fid * 8] = v;
    }
    __syncthreads();

    const int wv   = t >> 6;
    const int lane = t & 63;
    const int lr   = lane & 15;
    const int lhi  = lane >> 4;

    f32x4 acc = { 0.f, 0.f, 0.f, 0.f };
#pragma unroll
    for (int kh = 0; kh < 3; ++kh)
#pragma unroll
        for (int kw = 0; kw < 3; ++kw) {
            const int tap = kh * 3 + kw;
            const int R   = kh * 66 + wv * 16 + lr + kw;
#pragma unroll
            for (int half = 0; half < 2; ++half) {
                s16x8 a   = ld8(&s_t[lbase(R, half * 32 + lhi * 8)]);
                s16x8 bfr = ld8(&s_bf[((tap * 2 + half) * 64 + lane) * 8]);
                acc = mfma16(a, bfr, acc);
            }
        }

    if (lr < 3) {
        const int co = lr;
        const int wp = wv * 16 + lhi * 4;
        size_t o0 = (size_t)b * 3 * 65536 + (size_t)co * 65536 + (size_t)h * 256 + w0 + wp;
        float4 xv = *(const float4*)&x[o0];
        float bias = bu[co];
        float4 ov;
        ov.x = acc[0] + bias + xv.x;
        ov.y = acc[1] + bias + xv.y;
        ov.z = acc[2] + bias + xv.z;
        ov.w = acc[3] + bias + xv.w;
        *(float4*)&out[o0] = ov;
    }
}

// ---------------------------------------------------------------------------
extern "C" void kernel_launch(void* const* d_in, const int* in_sizes, int n_in,
                              void* d_out, int out_size, void* d_ws, size_t ws_size,
                              hipStream_t stream)
{
    const float* x     = (const float*)d_in[0];
    const float* cew   = (const float*)d_in[1];
    const float* ceb   = (const float*)d_in[2];
    const float* n1g   = (const float*)d_in[3];
    const float* n1b   = (const float*)d_in[4];
    const float* qkvw  = (const float*)d_in[5];
    const float* qkvb  = (const float*)d_in[6];
    const float* projw = (const float*)d_in[7];
    const float* projb = (const float*)d_in[8];
    const float* n2g   = (const float*)d_in[9];
    const float* n2b   = (const float*)d_in[10];
    const float* fc1w  = (const float*)d_in[11];
    const float* fc1b  = (const float*)d_in[12];
    const float* fc2w  = (const float*)d_in[13];
    const float* fc2b  = (const float*)d_in[14];
    const float* cuw   = (const float*)d_in[15];
    const float* cub   = (const float*)d_in[16];
    float* out = (float*)d_out;

    const size_t planeElems = (size_t)B_ * H_ * W_ * ED_;   // 33.5M
    bf16* xe = (bf16*)d_ws;
    bf16* xf = (bf16*)((char*)d_ws + planeElems * sizeof(bf16));

    // Fragment-layout bf16 weights live in d_out head (read by attn_mlp only;
    // conv_up fully overwrites d_out at the end of the launch).
    short* wb = (short*)d_out;

    hipLaunchKernelGGL(k_prep, dim3(NFRAG * 64 / 256), dim3(256), 0, stream,
                       qkvw, projw, fc1w, fc2w, wb);
    hipLaunchKernelGGL(k_conv_embed, dim3(2048), dim3(256), 0, stream, x, cew, ceb, xe);
    hipLaunchKernelGGL(k_attn_mlp,   dim3(8192), dim3(256), 0, stream,
                       xe, wb + WQ_OFF, qkvb, wb + WP_OFF, projb, n1g, n1b,
                       wb + W1_OFF, fc1b, wb + W2_OFF, fc2b, n2g, n2b, xf);
    hipLaunchKernelGGL(k_conv_up,    dim3(8192), dim3(256), 0, stream, x, xf, cuw, cub, out);
}